// Round 1
// baseline (824.309 us; speedup 1.0000x reference)
//
#include <hip/hip_runtime.h>
#include <math.h>

#define B_      4
#define L_      2048
#define IN_DIM  128
#define D_MODEL 256
#define OUT_DIM 128
#define D_STATE 16
#define D_INNER 768
#define NHEADS  256
#define HEADDIM 3
#define CONV_DIM 800
#define D_IN_PROJ 1824

// ---------------------------------------------------------------------------
// K1: input conv (kernel 4, pad (1,2)) fused with transpose -> u[b][l][o]
// u[b,l,o] = sum_{i,k} x[b,i,l+k-1] * conv_w[o,i,k] + conv_b[o]
// ---------------------------------------------------------------------------
__global__ __launch_bounds__(256) void conv_in_kernel(
    const float* __restrict__ x, const float* __restrict__ w,
    const float* __restrict__ bias, float* __restrict__ u)
{
    __shared__ float xs[IN_DIM][19];           // l window: l0-1 .. l0+17
    int b  = blockIdx.x >> 7;                  // / (L/16)
    int lt = blockIdx.x & 127;
    int l0 = lt * 16;
    int t  = threadIdx.x;                      // output channel o

    const float* xb = x + (size_t)b * IN_DIM * L_;
    for (int idx = t; idx < IN_DIM * 19; idx += 256) {
        int i = idx / 19, j = idx % 19;
        int l = l0 - 1 + j;
        xs[i][j] = (l >= 0 && l < L_) ? xb[(size_t)i * L_ + l] : 0.f;
    }
    __syncthreads();

    float acc[16];
    float bo = bias[t];
    #pragma unroll
    for (int dl = 0; dl < 16; ++dl) acc[dl] = bo;

    const float4* wo = (const float4*)(w + (size_t)t * (IN_DIM * 4));
    for (int i = 0; i < IN_DIM; ++i) {
        float4 wv = wo[i];
        float r[19];
        #pragma unroll
        for (int j = 0; j < 19; ++j) r[j] = xs[i][j];
        #pragma unroll
        for (int dl = 0; dl < 16; ++dl) {
            acc[dl] = fmaf(r[dl + 0], wv.x, acc[dl]);
            acc[dl] = fmaf(r[dl + 1], wv.y, acc[dl]);
            acc[dl] = fmaf(r[dl + 2], wv.z, acc[dl]);
            acc[dl] = fmaf(r[dl + 3], wv.w, acc[dl]);
        }
    }
    float* ub = u + ((size_t)(b * L_ + l0)) * D_MODEL + t;
    #pragma unroll
    for (int dl = 0; dl < 16; ++dl) ub[(size_t)dl * D_MODEL] = acc[dl];
}

// ---------------------------------------------------------------------------
// K2: generic fp32 GEMM  C[M,N] = A[M,K] * Bw[K,N]   (row-major all)
// 64x64 tile, 256 threads, 4x4 micro-tile, TK=16. M%64==0, K%16==0; N guarded.
// ---------------------------------------------------------------------------
__global__ __launch_bounds__(256) void gemm_f32_kernel(
    const float* __restrict__ A, const float* __restrict__ Bw,
    float* __restrict__ C, int M, int N, int K)
{
    __shared__ float As[16][64];
    __shared__ float Bs[16][64];
    int m0 = blockIdx.y * 64;
    int n0 = blockIdx.x * 64;
    int t  = threadIdx.x;
    int tm = t & 15, tn = t >> 4;

    int la_m = t >> 2, la_k = (t & 3) * 4;
    int lb_k = t >> 4, lb_n = (t & 15) * 4;

    float acc[4][4];
    #pragma unroll
    for (int i = 0; i < 4; ++i)
        #pragma unroll
        for (int j = 0; j < 4; ++j) acc[i][j] = 0.f;

    for (int k0 = 0; k0 < K; k0 += 16) {
        float4 av = *(const float4*)&A[(size_t)(m0 + la_m) * K + k0 + la_k];
        float4 bv = make_float4(0.f, 0.f, 0.f, 0.f);
        if (n0 + lb_n < N)
            bv = *(const float4*)&Bw[(size_t)(k0 + lb_k) * N + n0 + lb_n];
        __syncthreads();
        As[la_k + 0][la_m] = av.x;
        As[la_k + 1][la_m] = av.y;
        As[la_k + 2][la_m] = av.z;
        As[la_k + 3][la_m] = av.w;
        *(float4*)&Bs[lb_k][lb_n] = bv;
        __syncthreads();
        #pragma unroll
        for (int k = 0; k < 16; ++k) {
            float4 a = *(const float4*)&As[k][tm * 4];
            float4 b = *(const float4*)&Bs[k][tn * 4];
            acc[0][0] = fmaf(a.x, b.x, acc[0][0]);
            acc[0][1] = fmaf(a.x, b.y, acc[0][1]);
            acc[0][2] = fmaf(a.x, b.z, acc[0][2]);
            acc[0][3] = fmaf(a.x, b.w, acc[0][3]);
            acc[1][0] = fmaf(a.y, b.x, acc[1][0]);
            acc[1][1] = fmaf(a.y, b.y, acc[1][1]);
            acc[1][2] = fmaf(a.y, b.z, acc[1][2]);
            acc[1][3] = fmaf(a.y, b.w, acc[1][3]);
            acc[2][0] = fmaf(a.z, b.x, acc[2][0]);
            acc[2][1] = fmaf(a.z, b.y, acc[2][1]);
            acc[2][2] = fmaf(a.z, b.z, acc[2][2]);
            acc[2][3] = fmaf(a.z, b.w, acc[2][3]);
            acc[3][0] = fmaf(a.w, b.x, acc[3][0]);
            acc[3][1] = fmaf(a.w, b.y, acc[3][1]);
            acc[3][2] = fmaf(a.w, b.z, acc[3][2]);
            acc[3][3] = fmaf(a.w, b.w, acc[3][3]);
        }
    }
    #pragma unroll
    for (int i = 0; i < 4; ++i) {
        int m = m0 + tm * 4 + i;
        #pragma unroll
        for (int j = 0; j < 4; ++j) {
            int nn = n0 + tn * 4 + j;
            if (nn < N) C[(size_t)m * N + nn] = acc[i][j];
        }
    }
}

// ---------------------------------------------------------------------------
// K3: dt = softplus(dt_raw + dt_bias)    [B*L, 256]
// ---------------------------------------------------------------------------
__global__ __launch_bounds__(256) void dt_kernel(
    const float* __restrict__ zx, const float* __restrict__ dt_bias,
    float* __restrict__ dtb)
{
    int idx = blockIdx.x * 256 + threadIdx.x;   // over B*L*256
    int h  = idx & 255;
    int bl = idx >> 8;
    float v = zx[(size_t)bl * D_IN_PROJ + (D_INNER + CONV_DIM) + h] + dt_bias[h];
    float sp = (v > 20.f) ? v : log1pf(expf(v));
    dtb[idx] = sp;
}

// ---------------------------------------------------------------------------
// K4: causal depthwise conv (kernel 4) + bias + SiLU  -> xBCs[b][l][c], c<800
// ---------------------------------------------------------------------------
__global__ __launch_bounds__(256) void dwconv_kernel(
    const float* __restrict__ zx, const float* __restrict__ w,
    const float* __restrict__ bias, float* __restrict__ xBCs)
{
    int idx = blockIdx.x * 256 + threadIdx.x;   // over B*L*800
    int c  = idx % CONV_DIM;
    int bl = idx / CONV_DIM;
    int b = bl / L_, l = bl % L_;
    float4 wv = *(const float4*)&w[c * 4];
    float acc = bias[c];
    const float* base = zx + (size_t)(b * L_) * D_IN_PROJ + D_INNER + c;
    if (l - 3 >= 0) acc = fmaf(base[(size_t)(l - 3) * D_IN_PROJ], wv.x, acc);
    if (l - 2 >= 0) acc = fmaf(base[(size_t)(l - 2) * D_IN_PROJ], wv.y, acc);
    if (l - 1 >= 0) acc = fmaf(base[(size_t)(l - 1) * D_IN_PROJ], wv.z, acc);
    acc = fmaf(base[(size_t)l * D_IN_PROJ], wv.w, acc);
    float s = acc / (1.f + expf(-acc));         // silu
    xBCs[idx] = s;
}

// ---------------------------------------------------------------------------
// K5: SSD scan. One wave per (b,h). lane = p*16+n (p<3 active). State [3][16]
// in registers (1 float/lane). Register-chunk prefetch of 8 steps.
// y[b,l,h*3+p] = sum_n state*C + D*x
// ---------------------------------------------------------------------------
__global__ __launch_bounds__(256) void scan_kernel(
    const float* __restrict__ xBCs, const float* __restrict__ dtb,
    const float* __restrict__ A_log, const float* __restrict__ Dp,
    float* __restrict__ y)
{
    int wv   = (blockIdx.x * 256 + threadIdx.x) >> 6;   // 0..1023
    int lane = threadIdx.x & 63;
    int b = wv >> 8, h = wv & 255;
    int p = lane >> 4, n = lane & 15;
    int pc = (p < 3) ? p : 2;
    int h3p = h * 3 + pc;
    bool store_ok = (n == 0) && (p < 3);

    float A  = -expf(A_log[h]);
    float Dh = Dp[h];

    const float* xrow  = xBCs + (size_t)(b * L_) * CONV_DIM;
    const float* dtrow = dtb  + (size_t)(b * L_) * NHEADS + h;
    float*       yrow  = y    + (size_t)(b * L_) * D_INNER + h3p;

    float state = 0.f;
    const int CH = 8;
    const int NC = L_ / CH;      // 256

    float d0[CH], B0[CH], C0[CH], x0[CH];
    float d1[CH], B1[CH], C1[CH], x1[CH];

    auto load_chunk = [&](int c, float (&dd)[CH], float (&BB)[CH],
                          float (&CC)[CH], float (&xx)[CH]) {
        int l0 = c * CH;
        #pragma unroll
        for (int j = 0; j < CH; ++j) {
            const float* r = xrow + (size_t)(l0 + j) * CONV_DIM;
            dd[j] = dtrow[(size_t)(l0 + j) * NHEADS];
            BB[j] = r[D_INNER + n];
            CC[j] = r[D_INNER + D_STATE + n];
            xx[j] = r[h3p];
        }
    };
    auto compute_chunk = [&](int c, float (&dd)[CH], float (&BB)[CH],
                             float (&CC)[CH], float (&xx)[CH]) {
        int l0 = c * CH;
        #pragma unroll
        for (int j = 0; j < CH; ++j) {
            float dtv = dd[j];
            float dA  = __expf(dtv * A);
            float dBx = dtv * xx[j] * BB[j];
            state = fmaf(state, dA, dBx);
            float tt = state * CC[j];
            tt += __shfl_xor(tt, 8);
            tt += __shfl_xor(tt, 4);
            tt += __shfl_xor(tt, 2);
            tt += __shfl_xor(tt, 1);
            if (store_ok)
                yrow[(size_t)(l0 + j) * D_INNER] = fmaf(Dh, xx[j], tt);
        }
    };

    load_chunk(0, d0, B0, C0, x0);
    for (int c = 0; c < NC; c += 2) {
        load_chunk(c + 1, d1, B1, C1, x1);
        compute_chunk(c, d0, B0, C0, x0);
        if (c + 2 < NC) load_chunk(c + 2, d0, B0, C0, x0);
        compute_chunk(c + 1, d1, B1, C1, x1);
    }
}

// ---------------------------------------------------------------------------
// K6: y = y * silu(z); RMSNorm over 768; * norm_w.   In-place on y.
// One block (256 thr) per (b,l) row; 3 elements/thread.
// ---------------------------------------------------------------------------
__global__ __launch_bounds__(256) void gate_norm_kernel(
    const float* __restrict__ zx, const float* __restrict__ norm_w,
    float* __restrict__ y)
{
    int bl = blockIdx.x;
    int t  = threadIdx.x;
    const float* zrow = zx + (size_t)bl * D_IN_PROJ;
    float* yrow = y + (size_t)bl * D_INNER;

    float v[3];
    float ss = 0.f;
    #pragma unroll
    for (int j = 0; j < 3; ++j) {
        int i = t + j * 256;
        float z = zrow[i];
        float s = z / (1.f + expf(-z));
        float val = yrow[i] * s;
        v[j] = val;
        ss += val * val;
    }
    ss += __shfl_xor(ss, 32);
    ss += __shfl_xor(ss, 16);
    ss += __shfl_xor(ss, 8);
    ss += __shfl_xor(ss, 4);
    ss += __shfl_xor(ss, 2);
    ss += __shfl_xor(ss, 1);
    __shared__ float red[4];
    int lane = t & 63, wid = t >> 6;
    if (lane == 0) red[wid] = ss;
    __syncthreads();
    float tot = red[0] + red[1] + red[2] + red[3];
    float rs = rsqrtf(tot * (1.f / D_INNER) + 1e-5f);
    #pragma unroll
    for (int j = 0; j < 3; ++j) {
        int i = t + j * 256;
        yrow[i] = v[j] * rs * norm_w[i];
    }
}

// ---------------------------------------------------------------------------
// K8: output conv (kernel 4, pad (1,2)) with transpose:
// out[b,o,l] = sum_{c,k} tmp[b,l+k-1,c] * out_conv_w[o,c,k]
// ---------------------------------------------------------------------------
__global__ __launch_bounds__(128) void conv_out_kernel(
    const float* __restrict__ tmp, const float* __restrict__ w,
    float* __restrict__ out)
{
    __shared__ float ts[19][D_MODEL];
    int b  = blockIdx.x >> 7;
    int lt = blockIdx.x & 127;
    int l0 = lt * 16;
    int t  = threadIdx.x;                       // o in 0..127

    const float* tb = tmp + (size_t)(b * L_) * D_MODEL;
    for (int idx = t; idx < 19 * D_MODEL; idx += 128) {
        int j = idx >> 8, c = idx & 255;
        int l = l0 - 1 + j;
        ts[j][c] = (l >= 0 && l < L_) ? tb[(size_t)l * D_MODEL + c] : 0.f;
    }
    __syncthreads();

    float acc[16];
    #pragma unroll
    for (int dl = 0; dl < 16; ++dl) acc[dl] = 0.f;

    const float4* wo = (const float4*)(w + (size_t)t * (D_MODEL * 4));
    for (int c = 0; c < D_MODEL; ++c) {
        float4 wv = wo[c];
        float r[19];
        #pragma unroll
        for (int j = 0; j < 19; ++j) r[j] = ts[j][c];
        #pragma unroll
        for (int dl = 0; dl < 16; ++dl) {
            acc[dl] = fmaf(r[dl + 0], wv.x, acc[dl]);
            acc[dl] = fmaf(r[dl + 1], wv.y, acc[dl]);
            acc[dl] = fmaf(r[dl + 2], wv.z, acc[dl]);
            acc[dl] = fmaf(r[dl + 3], wv.w, acc[dl]);
        }
    }
    float* ob = out + ((size_t)b * OUT_DIM + t) * L_ + l0;
    #pragma unroll
    for (int dl = 0; dl < 16; ++dl) ob[dl] = acc[dl];
}

// ---------------------------------------------------------------------------
extern "C" void kernel_launch(void* const* d_in, const int* in_sizes, int n_in,
                              void* d_out, int out_size, void* d_ws, size_t ws_size,
                              hipStream_t stream)
{
    const float* x           = (const float*)d_in[0];
    const float* conv_w      = (const float*)d_in[1];
    const float* conv_b      = (const float*)d_in[2];
    const float* in_proj_w   = (const float*)d_in[3];
    const float* dw_conv_w   = (const float*)d_in[4];
    const float* dw_conv_b   = (const float*)d_in[5];
    const float* dt_bias     = (const float*)d_in[6];
    const float* A_log       = (const float*)d_in[7];
    const float* Dp          = (const float*)d_in[8];
    const float* norm_w      = (const float*)d_in[9];
    const float* mamba_out_w = (const float*)d_in[10];
    const float* out_conv_w  = (const float*)d_in[11];
    float* out = (float*)d_out;
    float* ws  = (float*)d_ws;

    // workspace layout (floats)
    float* u    = ws;                        // 4*2048*256   = 2,097,152
    float* zx   = u    + 2097152;            // 4*2048*1824  = 14,942,208
    float* xBCs = zx   + 14942208;           // 4*2048*800   = 6,553,600
    float* dtb  = xBCs + 6553600;            // 4*2048*256   = 2,097,152
    float* ybuf = dtb  + 2097152;            // 4*2048*768   = 6,291,456
    float* tmp2 = u;                         // alias: u is dead after in_proj

    // 1. input conv -> u [B,L,256]
    conv_in_kernel<<<B_ * (L_ / 16), 256, 0, stream>>>(x, conv_w, conv_b, u);

    // 2. in_proj GEMM: zx[8192,1824] = u[8192,256] @ in_proj_w[256,1824]
    gemm_f32_kernel<<<dim3((D_IN_PROJ + 63) / 64, (B_ * L_) / 64), 256, 0, stream>>>(
        u, in_proj_w, zx, B_ * L_, D_IN_PROJ, D_MODEL);

    // 3. dt = softplus(dt_raw + bias)
    dt_kernel<<<(B_ * L_ * NHEADS) / 256, 256, 0, stream>>>(zx, dt_bias, dtb);

    // 4. depthwise conv + silu -> xBCs [B,L,800]
    dwconv_kernel<<<(B_ * L_ * CONV_DIM) / 256, 256, 0, stream>>>(
        zx, dw_conv_w, dw_conv_b, xBCs);

    // 5. SSD scan -> ybuf [B,L,768]
    scan_kernel<<<(B_ * NHEADS * 64) / 256, 256, 0, stream>>>(
        xBCs, dtb, A_log, Dp, ybuf);

    // 6. gating + RMSNorm (in place on ybuf)
    gate_norm_kernel<<<B_ * L_, 256, 0, stream>>>(zx, norm_w, ybuf);

    // 7. out GEMM: tmp2[8192,256] = ybuf[8192,768] @ mamba_out_w[768,256]
    gemm_f32_kernel<<<dim3(D_MODEL / 64, (B_ * L_) / 64), 256, 0, stream>>>(
        ybuf, mamba_out_w, tmp2, B_ * L_, D_MODEL, D_INNER);

    // 8. output conv -> out [B,128,2048]
    conv_out_kernel<<<B_ * (L_ / 16), 128, 0, stream>>>(tmp2, out_conv_w, out);
}

// Round 2
// 720.654 us; speedup vs baseline: 1.1438x; 1.1438x over previous
//
#include <hip/hip_runtime.h>
#include <math.h>

#define B_      4
#define L_      2048
#define IN_DIM  128
#define D_MODEL 256
#define OUT_DIM 128
#define D_STATE 16
#define D_INNER 768
#define NHEADS  256
#define HEADDIM 3
#define CONV_DIM 800
#define D_IN_PROJ 1824

#define SCAN_NC 32      // chunks per sequence
#define SCAN_CL 64      // steps per chunk (SCAN_NC*SCAN_CL == L_)

// ---------------------------------------------------------------------------
// K1: input conv (kernel 4, pad (1,2)) fused with transpose -> u[b][l][o]
// ---------------------------------------------------------------------------
__global__ __launch_bounds__(256) void conv_in_kernel(
    const float* __restrict__ x, const float* __restrict__ w,
    const float* __restrict__ bias, float* __restrict__ u)
{
    __shared__ float xs[IN_DIM][19];           // l window: l0-1 .. l0+17
    int b  = blockIdx.x >> 7;
    int lt = blockIdx.x & 127;
    int l0 = lt * 16;
    int t  = threadIdx.x;                      // output channel o

    const float* xb = x + (size_t)b * IN_DIM * L_;
    for (int idx = t; idx < IN_DIM * 19; idx += 256) {
        int i = idx / 19, j = idx % 19;
        int l = l0 - 1 + j;
        xs[i][j] = (l >= 0 && l < L_) ? xb[(size_t)i * L_ + l] : 0.f;
    }
    __syncthreads();

    float acc[16];
    float bo = bias[t];
    #pragma unroll
    for (int dl = 0; dl < 16; ++dl) acc[dl] = bo;

    const float4* wo = (const float4*)(w + (size_t)t * (IN_DIM * 4));
    for (int i = 0; i < IN_DIM; ++i) {
        float4 wv = wo[i];
        float r[19];
        #pragma unroll
        for (int j = 0; j < 19; ++j) r[j] = xs[i][j];
        #pragma unroll
        for (int dl = 0; dl < 16; ++dl) {
            acc[dl] = fmaf(r[dl + 0], wv.x, acc[dl]);
            acc[dl] = fmaf(r[dl + 1], wv.y, acc[dl]);
            acc[dl] = fmaf(r[dl + 2], wv.z, acc[dl]);
            acc[dl] = fmaf(r[dl + 3], wv.w, acc[dl]);
        }
    }
    float* ub = u + ((size_t)(b * L_ + l0)) * D_MODEL + t;
    #pragma unroll
    for (int dl = 0; dl < 16; ++dl) ub[(size_t)dl * D_MODEL] = acc[dl];
}

// ---------------------------------------------------------------------------
// K2: generic fp32 GEMM  C[M,N] = A[M,K] * Bw[K,N]   (row-major all)
// ---------------------------------------------------------------------------
__global__ __launch_bounds__(256) void gemm_f32_kernel(
    const float* __restrict__ A, const float* __restrict__ Bw,
    float* __restrict__ C, int M, int N, int K)
{
    __shared__ float As[16][64];
    __shared__ float Bs[16][64];
    int m0 = blockIdx.y * 64;
    int n0 = blockIdx.x * 64;
    int t  = threadIdx.x;
    int tm = t & 15, tn = t >> 4;

    int la_m = t >> 2, la_k = (t & 3) * 4;
    int lb_k = t >> 4, lb_n = (t & 15) * 4;

    float acc[4][4];
    #pragma unroll
    for (int i = 0; i < 4; ++i)
        #pragma unroll
        for (int j = 0; j < 4; ++j) acc[i][j] = 0.f;

    for (int k0 = 0; k0 < K; k0 += 16) {
        float4 av = *(const float4*)&A[(size_t)(m0 + la_m) * K + k0 + la_k];
        float4 bv = make_float4(0.f, 0.f, 0.f, 0.f);
        if (n0 + lb_n < N)
            bv = *(const float4*)&Bw[(size_t)(k0 + lb_k) * N + n0 + lb_n];
        __syncthreads();
        As[la_k + 0][la_m] = av.x;
        As[la_k + 1][la_m] = av.y;
        As[la_k + 2][la_m] = av.z;
        As[la_k + 3][la_m] = av.w;
        *(float4*)&Bs[lb_k][lb_n] = bv;
        __syncthreads();
        #pragma unroll
        for (int k = 0; k < 16; ++k) {
            float4 a = *(const float4*)&As[k][tm * 4];
            float4 b = *(const float4*)&Bs[k][tn * 4];
            acc[0][0] = fmaf(a.x, b.x, acc[0][0]);
            acc[0][1] = fmaf(a.x, b.y, acc[0][1]);
            acc[0][2] = fmaf(a.x, b.z, acc[0][2]);
            acc[0][3] = fmaf(a.x, b.w, acc[0][3]);
            acc[1][0] = fmaf(a.y, b.x, acc[1][0]);
            acc[1][1] = fmaf(a.y, b.y, acc[1][1]);
            acc[1][2] = fmaf(a.y, b.z, acc[1][2]);
            acc[1][3] = fmaf(a.y, b.w, acc[1][3]);
            acc[2][0] = fmaf(a.z, b.x, acc[2][0]);
            acc[2][1] = fmaf(a.z, b.y, acc[2][1]);
            acc[2][2] = fmaf(a.z, b.z, acc[2][2]);
            acc[2][3] = fmaf(a.z, b.w, acc[2][3]);
            acc[3][0] = fmaf(a.w, b.x, acc[3][0]);
            acc[3][1] = fmaf(a.w, b.y, acc[3][1]);
            acc[3][2] = fmaf(a.w, b.z, acc[3][2]);
            acc[3][3] = fmaf(a.w, b.w, acc[3][3]);
        }
    }
    #pragma unroll
    for (int i = 0; i < 4; ++i) {
        int m = m0 + tm * 4 + i;
        #pragma unroll
        for (int j = 0; j < 4; ++j) {
            int nn = n0 + tn * 4 + j;
            if (nn < N) C[(size_t)m * N + nn] = acc[i][j];
        }
    }
}

// ---------------------------------------------------------------------------
// K3: dt = softplus(dt_raw + dt_bias)    [B*L, 256]
// ---------------------------------------------------------------------------
__global__ __launch_bounds__(256) void dt_kernel(
    const float* __restrict__ zx, const float* __restrict__ dt_bias,
    float* __restrict__ dtb)
{
    int idx = blockIdx.x * 256 + threadIdx.x;
    int h  = idx & 255;
    int bl = idx >> 8;
    float v = zx[(size_t)bl * D_IN_PROJ + (D_INNER + CONV_DIM) + h] + dt_bias[h];
    float sp = (v > 20.f) ? v : log1pf(expf(v));
    dtb[idx] = sp;
}

// ---------------------------------------------------------------------------
// K4: causal depthwise conv (kernel 4) + bias + SiLU  -> xBCs[b][l][c], c<800
// ---------------------------------------------------------------------------
__global__ __launch_bounds__(256) void dwconv_kernel(
    const float* __restrict__ zx, const float* __restrict__ w,
    const float* __restrict__ bias, float* __restrict__ xBCs)
{
    int idx = blockIdx.x * 256 + threadIdx.x;
    int c  = idx % CONV_DIM;
    int bl = idx / CONV_DIM;
    int b = bl / L_, l = bl % L_;
    float4 wv = *(const float4*)&w[c * 4];
    float acc = bias[c];
    const float* base = zx + (size_t)(b * L_) * D_IN_PROJ + D_INNER + c;
    if (l - 3 >= 0) acc = fmaf(base[(size_t)(l - 3) * D_IN_PROJ], wv.x, acc);
    if (l - 2 >= 0) acc = fmaf(base[(size_t)(l - 2) * D_IN_PROJ], wv.y, acc);
    if (l - 1 >= 0) acc = fmaf(base[(size_t)(l - 1) * D_IN_PROJ], wv.z, acc);
    acc = fmaf(base[(size_t)l * D_IN_PROJ], wv.w, acc);
    float s = acc / (1.f + expf(-acc));
    xBCs[idx] = s;
}

// ---------------------------------------------------------------------------
// K5a: per-chunk local scan (initial state 0). One wave per (b,h,c).
// lane=(p,n), p<3 active. Outputs chunk-final state Sloc[bh][c][48] and
// per-chunk decay product prodA[bh][c].
// wave index: ((b*NC + c)*H + h)  -- h fastest for B-row / dt L2 locality.
// ---------------------------------------------------------------------------
__global__ __launch_bounds__(256) void scan_local_kernel(
    const float* __restrict__ xBCs, const float* __restrict__ dtb,
    const float* __restrict__ A_log,
    float* __restrict__ Sloc, float* __restrict__ prodA)
{
    int wv   = blockIdx.x * 4 + (threadIdx.x >> 6);
    int lane = threadIdx.x & 63;
    int h = wv & 255;
    int c = (wv >> 8) & (SCAN_NC - 1);
    int b = wv >> 13;
    int p = lane >> 4, n = lane & 15;
    int pc = (p < 3) ? p : 2;
    int h3p = h * 3 + pc;

    float A = -expf(A_log[h]);
    const float* xrow  = xBCs + ((size_t)(b * L_) + c * SCAN_CL) * CONV_DIM;
    const float* dtrow = dtb  + ((size_t)(b * L_) + c * SCAN_CL) * NHEADS + h;

    float state = 0.f, prod = 1.f;
    const int CH = 8;
    float d0[CH], B0[CH], x0[CH];
    float d1[CH], B1[CH], x1[CH];

    auto load_chunk = [&](int s, float (&dd)[CH], float (&BB)[CH], float (&xx)[CH]) {
        int l0 = s * CH;
        #pragma unroll
        for (int j = 0; j < CH; ++j) {
            const float* r = xrow + (size_t)(l0 + j) * CONV_DIM;
            dd[j] = dtrow[(size_t)(l0 + j) * NHEADS];
            BB[j] = r[D_INNER + n];
            xx[j] = r[h3p];
        }
    };
    auto compute_chunk = [&](float (&dd)[CH], float (&BB)[CH], float (&xx)[CH]) {
        #pragma unroll
        for (int j = 0; j < CH; ++j) {
            float dtv = dd[j];
            float dA  = __expf(dtv * A);
            prod *= dA;
            state = fmaf(state, dA, dtv * xx[j] * BB[j]);
        }
    };

    const int NS = SCAN_CL / CH;   // 8 sub-chunks
    load_chunk(0, d0, B0, x0);
    for (int s = 0; s < NS; s += 2) {
        load_chunk(s + 1, d1, B1, x1);
        compute_chunk(d0, B0, x0);
        if (s + 2 < NS) load_chunk(s + 2, d0, B0, x0);
        compute_chunk(d1, B1, x1);
    }

    size_t bh = (size_t)(b * NHEADS + h);
    if (p < 3) Sloc[(bh * SCAN_NC + c) * 48 + p * 16 + n] = state;
    if (lane == 0) prodA[bh * SCAN_NC + c] = prod;
}

// ---------------------------------------------------------------------------
// K5b: sequential prefix over chunks, in place on Sloc.
// After this, Sloc[bh][c] holds the TRUE initial state for chunk c.
// One wave per (b,h).
// ---------------------------------------------------------------------------
__global__ __launch_bounds__(256) void scan_prefix_kernel(
    float* __restrict__ Sloc, const float* __restrict__ prodA)
{
    int wv   = blockIdx.x * 4 + (threadIdx.x >> 6);   // 0..1023 = b*256+h
    int lane = threadIdx.x & 63;
    int p = lane >> 4, n = lane & 15;
    bool act = (p < 3);
    int l48 = ((p < 3) ? p : 2) * 16 + n;
    size_t base = (size_t)wv * SCAN_NC;

    float cur = 0.f;
    for (int c = 0; c < SCAN_NC; ++c) {
        float s  = Sloc[(base + c) * 48 + l48];
        float pa = prodA[base + c];
        if (act) Sloc[(base + c) * 48 + l48] = cur;
        cur = fmaf(pa, cur, s);
    }
}

// ---------------------------------------------------------------------------
// K5c: final scan with true initial state; writes y. One wave per (b,h,c).
// ---------------------------------------------------------------------------
__global__ __launch_bounds__(256) void scan_final_kernel(
    const float* __restrict__ xBCs, const float* __restrict__ dtb,
    const float* __restrict__ A_log, const float* __restrict__ Dp,
    const float* __restrict__ Sinit, float* __restrict__ y)
{
    int wv   = blockIdx.x * 4 + (threadIdx.x >> 6);
    int lane = threadIdx.x & 63;
    int h = wv & 255;
    int c = (wv >> 8) & (SCAN_NC - 1);
    int b = wv >> 13;
    int p = lane >> 4, n = lane & 15;
    int pc = (p < 3) ? p : 2;
    int h3p = h * 3 + pc;
    bool store_ok = (n == 0) && (p < 3);

    float A  = -expf(A_log[h]);
    float Dh = Dp[h];
    const float* xrow  = xBCs + ((size_t)(b * L_) + c * SCAN_CL) * CONV_DIM;
    const float* dtrow = dtb  + ((size_t)(b * L_) + c * SCAN_CL) * NHEADS + h;
    float*       yrow  = y    + ((size_t)(b * L_) + c * SCAN_CL) * D_INNER + h3p;

    size_t bh = (size_t)(b * NHEADS + h);
    float state = Sinit[(bh * SCAN_NC + c) * 48 + pc * 16 + n];

    const int CH = 8;
    float d0[CH], B0[CH], C0[CH], x0[CH];
    float d1[CH], B1[CH], C1[CH], x1[CH];

    auto load_chunk = [&](int s, float (&dd)[CH], float (&BB)[CH],
                          float (&CC)[CH], float (&xx)[CH]) {
        int l0 = s * CH;
        #pragma unroll
        for (int j = 0; j < CH; ++j) {
            const float* r = xrow + (size_t)(l0 + j) * CONV_DIM;
            dd[j] = dtrow[(size_t)(l0 + j) * NHEADS];
            BB[j] = r[D_INNER + n];
            CC[j] = r[D_INNER + D_STATE + n];
            xx[j] = r[h3p];
        }
    };
    auto compute_chunk = [&](int s, float (&dd)[CH], float (&BB)[CH],
                             float (&CC)[CH], float (&xx)[CH]) {
        int l0 = s * CH;
        #pragma unroll
        for (int j = 0; j < CH; ++j) {
            float dtv = dd[j];
            float dA  = __expf(dtv * A);
            state = fmaf(state, dA, dtv * xx[j] * BB[j]);
            float tt = state * CC[j];
            tt += __shfl_xor(tt, 8);
            tt += __shfl_xor(tt, 4);
            tt += __shfl_xor(tt, 2);
            tt += __shfl_xor(tt, 1);
            if (store_ok)
                yrow[(size_t)(l0 + j) * D_INNER] = fmaf(Dh, xx[j], tt);
        }
    };

    const int NS = SCAN_CL / CH;
    load_chunk(0, d0, B0, C0, x0);
    for (int s = 0; s < NS; s += 2) {
        load_chunk(s + 1, d1, B1, C1, x1);
        compute_chunk(s, d0, B0, C0, x0);
        if (s + 2 < NS) load_chunk(s + 2, d0, B0, C0, x0);
        compute_chunk(s + 1, d1, B1, C1, x1);
    }
}

// ---------------------------------------------------------------------------
// K6: y = y * silu(z); RMSNorm over 768; * norm_w.   In-place on y.
// ---------------------------------------------------------------------------
__global__ __launch_bounds__(256) void gate_norm_kernel(
    const float* __restrict__ zx, const float* __restrict__ norm_w,
    float* __restrict__ y)
{
    int bl = blockIdx.x;
    int t  = threadIdx.x;
    const float* zrow = zx + (size_t)bl * D_IN_PROJ;
    float* yrow = y + (size_t)bl * D_INNER;

    float v[3];
    float ss = 0.f;
    #pragma unroll
    for (int j = 0; j < 3; ++j) {
        int i = t + j * 256;
        float z = zrow[i];
        float s = z / (1.f + expf(-z));
        float val = yrow[i] * s;
        v[j] = val;
        ss += val * val;
    }
    ss += __shfl_xor(ss, 32);
    ss += __shfl_xor(ss, 16);
    ss += __shfl_xor(ss, 8);
    ss += __shfl_xor(ss, 4);
    ss += __shfl_xor(ss, 2);
    ss += __shfl_xor(ss, 1);
    __shared__ float red[4];
    int lane = t & 63, wid = t >> 6;
    if (lane == 0) red[wid] = ss;
    __syncthreads();
    float tot = red[0] + red[1] + red[2] + red[3];
    float rs = rsqrtf(tot * (1.f / D_INNER) + 1e-5f);
    #pragma unroll
    for (int j = 0; j < 3; ++j) {
        int i = t + j * 256;
        yrow[i] = v[j] * rs * norm_w[i];
    }
}

// ---------------------------------------------------------------------------
// K8: output conv (kernel 4, pad (1,2)) with transpose
// ---------------------------------------------------------------------------
__global__ __launch_bounds__(128) void conv_out_kernel(
    const float* __restrict__ tmp, const float* __restrict__ w,
    float* __restrict__ out)
{
    __shared__ float ts[19][D_MODEL];
    int b  = blockIdx.x >> 7;
    int lt = blockIdx.x & 127;
    int l0 = lt * 16;
    int t  = threadIdx.x;                       // o in 0..127

    const float* tb = tmp + (size_t)(b * L_) * D_MODEL;
    for (int idx = t; idx < 19 * D_MODEL; idx += 128) {
        int j = idx >> 8, c = idx & 255;
        int l = l0 - 1 + j;
        ts[j][c] = (l >= 0 && l < L_) ? tb[(size_t)l * D_MODEL + c] : 0.f;
    }
    __syncthreads();

    float acc[16];
    #pragma unroll
    for (int dl = 0; dl < 16; ++dl) acc[dl] = 0.f;

    const float4* wo = (const float4*)(w + (size_t)t * (D_MODEL * 4));
    for (int c = 0; c < D_MODEL; ++c) {
        float4 wv = wo[c];
        float r[19];
        #pragma unroll
        for (int j = 0; j < 19; ++j) r[j] = ts[j][c];
        #pragma unroll
        for (int dl = 0; dl < 16; ++dl) {
            acc[dl] = fmaf(r[dl + 0], wv.x, acc[dl]);
            acc[dl] = fmaf(r[dl + 1], wv.y, acc[dl]);
            acc[dl] = fmaf(r[dl + 2], wv.z, acc[dl]);
            acc[dl] = fmaf(r[dl + 3], wv.w, acc[dl]);
        }
    }
    float* ob = out + ((size_t)b * OUT_DIM + t) * L_ + l0;
    #pragma unroll
    for (int dl = 0; dl < 16; ++dl) ob[dl] = acc[dl];
}

// ---------------------------------------------------------------------------
extern "C" void kernel_launch(void* const* d_in, const int* in_sizes, int n_in,
                              void* d_out, int out_size, void* d_ws, size_t ws_size,
                              hipStream_t stream)
{
    const float* x           = (const float*)d_in[0];
    const float* conv_w      = (const float*)d_in[1];
    const float* conv_b      = (const float*)d_in[2];
    const float* in_proj_w   = (const float*)d_in[3];
    const float* dw_conv_w   = (const float*)d_in[4];
    const float* dw_conv_b   = (const float*)d_in[5];
    const float* dt_bias     = (const float*)d_in[6];
    const float* A_log       = (const float*)d_in[7];
    const float* Dp          = (const float*)d_in[8];
    const float* norm_w      = (const float*)d_in[9];
    const float* mamba_out_w = (const float*)d_in[10];
    const float* out_conv_w  = (const float*)d_in[11];
    float* out = (float*)d_out;
    float* ws  = (float*)d_ws;

    // workspace layout (floats)
    float* u    = ws;                        // 4*2048*256   = 2,097,152
    float* zx   = u    + 2097152;            // 4*2048*1824  = 14,942,208
    float* xBCs = zx   + 14942208;           // 4*2048*800   = 6,553,600
    float* dtb  = xBCs + 6553600;            // 4*2048*256   = 2,097,152
    float* ybuf = dtb  + 2097152;            // 4*2048*768   = 6,291,456
    // u region is dead after gemm1 and reused:
    //   Sloc  : 4*256*32*48 = 1,572,864 floats
    //   prodA : 4*256*32    =    32,768 floats   (total 1.6M < 2.09M of u)
    float* Sloc  = u;
    float* prodA = u + 1572864;
    float* tmp2  = u;                        // step 7 output (scan done by then)

    // 1. input conv -> u [B,L,256]
    conv_in_kernel<<<B_ * (L_ / 16), 256, 0, stream>>>(x, conv_w, conv_b, u);

    // 2. in_proj GEMM: zx[8192,1824] = u[8192,256] @ in_proj_w[256,1824]
    gemm_f32_kernel<<<dim3((D_IN_PROJ + 63) / 64, (B_ * L_) / 64), 256, 0, stream>>>(
        u, in_proj_w, zx, B_ * L_, D_IN_PROJ, D_MODEL);

    // 3. dt = softplus(dt_raw + bias)
    dt_kernel<<<(B_ * L_ * NHEADS) / 256, 256, 0, stream>>>(zx, dt_bias, dtb);

    // 4. depthwise conv + silu -> xBCs [B,L,800]
    dwconv_kernel<<<(B_ * L_ * CONV_DIM) / 256, 256, 0, stream>>>(
        zx, dw_conv_w, dw_conv_b, xBCs);

    // 5. chunked SSD scan -> ybuf [B,L,768]
    scan_local_kernel<<<(B_ * NHEADS * SCAN_NC) / 4, 256, 0, stream>>>(
        xBCs, dtb, A_log, Sloc, prodA);
    scan_prefix_kernel<<<(B_ * NHEADS) / 4, 256, 0, stream>>>(Sloc, prodA);
    scan_final_kernel<<<(B_ * NHEADS * SCAN_NC) / 4, 256, 0, stream>>>(
        xBCs, dtb, A_log, Dp, Sloc, ybuf);

    // 6. gating + RMSNorm (in place on ybuf)
    gate_norm_kernel<<<B_ * L_, 256, 0, stream>>>(zx, norm_w, ybuf);

    // 7. out GEMM: tmp2[8192,256] = ybuf[8192,768] @ mamba_out_w[768,256]
    gemm_f32_kernel<<<dim3(D_MODEL / 64, (B_ * L_) / 64), 256, 0, stream>>>(
        ybuf, mamba_out_w, tmp2, B_ * L_, D_MODEL, D_INNER);

    // 8. output conv -> out [B,128,2048]
    conv_out_kernel<<<B_ * (L_ / 16), 128, 0, stream>>>(tmp2, out_conv_w, out);
}

// Round 3
// 560.035 us; speedup vs baseline: 1.4719x; 1.2868x over previous
//
#include <hip/hip_runtime.h>
#include <math.h>

#define B_      4
#define L_      2048
#define IN_DIM  128
#define D_MODEL 256
#define OUT_DIM 128
#define D_STATE 16
#define D_INNER 768
#define NHEADS  256
#define HEADDIM 3
#define CONV_DIM 800
#define D_IN_PROJ 1824

#define SCAN_NC 32      // chunks per sequence
#define SCAN_CL 64      // steps per chunk

// ---------------------------------------------------------------------------
// K1: input conv (kernel 4, pad (1,2)) fused with transpose -> u[b][l][o]
// ---------------------------------------------------------------------------
__global__ __launch_bounds__(256) void conv_in_kernel(
    const float* __restrict__ x, const float* __restrict__ w,
    const float* __restrict__ bias, float* __restrict__ u)
{
    __shared__ float xs[IN_DIM][19];
    int b  = blockIdx.x >> 7;
    int lt = blockIdx.x & 127;
    int l0 = lt * 16;
    int t  = threadIdx.x;

    const float* xb = x + (size_t)b * IN_DIM * L_;
    for (int idx = t; idx < IN_DIM * 19; idx += 256) {
        int i = idx / 19, j = idx % 19;
        int l = l0 - 1 + j;
        xs[i][j] = (l >= 0 && l < L_) ? xb[(size_t)i * L_ + l] : 0.f;
    }
    __syncthreads();

    float acc[16];
    float bo = bias[t];
    #pragma unroll
    for (int dl = 0; dl < 16; ++dl) acc[dl] = bo;

    const float4* wo = (const float4*)(w + (size_t)t * (IN_DIM * 4));
    for (int i = 0; i < IN_DIM; ++i) {
        float4 wv = wo[i];
        float r[19];
        #pragma unroll
        for (int j = 0; j < 19; ++j) r[j] = xs[i][j];
        #pragma unroll
        for (int dl = 0; dl < 16; ++dl) {
            acc[dl] = fmaf(r[dl + 0], wv.x, acc[dl]);
            acc[dl] = fmaf(r[dl + 1], wv.y, acc[dl]);
            acc[dl] = fmaf(r[dl + 2], wv.z, acc[dl]);
            acc[dl] = fmaf(r[dl + 3], wv.w, acc[dl]);
        }
    }
    float* ub = u + ((size_t)(b * L_ + l0)) * D_MODEL + t;
    #pragma unroll
    for (int dl = 0; dl < 16; ++dl) ub[(size_t)dl * D_MODEL] = acc[dl];
}

// ---------------------------------------------------------------------------
// K2: generic fp32 GEMM  C[M,N] = A[M,K] * Bw[K,N]   (row-major all)
// ---------------------------------------------------------------------------
__global__ __launch_bounds__(256) void gemm_f32_kernel(
    const float* __restrict__ A, const float* __restrict__ Bw,
    float* __restrict__ C, int M, int N, int K)
{
    __shared__ float As[16][64];
    __shared__ float Bs[16][64];
    int m0 = blockIdx.y * 64;
    int n0 = blockIdx.x * 64;
    int t  = threadIdx.x;
    int tm = t & 15, tn = t >> 4;

    int la_m = t >> 2, la_k = (t & 3) * 4;
    int lb_k = t >> 4, lb_n = (t & 15) * 4;

    float acc[4][4];
    #pragma unroll
    for (int i = 0; i < 4; ++i)
        #pragma unroll
        for (int j = 0; j < 4; ++j) acc[i][j] = 0.f;

    for (int k0 = 0; k0 < K; k0 += 16) {
        float4 av = *(const float4*)&A[(size_t)(m0 + la_m) * K + k0 + la_k];
        float4 bv = make_float4(0.f, 0.f, 0.f, 0.f);
        if (n0 + lb_n < N)
            bv = *(const float4*)&Bw[(size_t)(k0 + lb_k) * N + n0 + lb_n];
        __syncthreads();
        As[la_k + 0][la_m] = av.x;
        As[la_k + 1][la_m] = av.y;
        As[la_k + 2][la_m] = av.z;
        As[la_k + 3][la_m] = av.w;
        *(float4*)&Bs[lb_k][lb_n] = bv;
        __syncthreads();
        #pragma unroll
        for (int k = 0; k < 16; ++k) {
            float4 a = *(const float4*)&As[k][tm * 4];
            float4 b = *(const float4*)&Bs[k][tn * 4];
            acc[0][0] = fmaf(a.x, b.x, acc[0][0]);
            acc[0][1] = fmaf(a.x, b.y, acc[0][1]);
            acc[0][2] = fmaf(a.x, b.z, acc[0][2]);
            acc[0][3] = fmaf(a.x, b.w, acc[0][3]);
            acc[1][0] = fmaf(a.y, b.x, acc[1][0]);
            acc[1][1] = fmaf(a.y, b.y, acc[1][1]);
            acc[1][2] = fmaf(a.y, b.z, acc[1][2]);
            acc[1][3] = fmaf(a.y, b.w, acc[1][3]);
            acc[2][0] = fmaf(a.z, b.x, acc[2][0]);
            acc[2][1] = fmaf(a.z, b.y, acc[2][1]);
            acc[2][2] = fmaf(a.z, b.z, acc[2][2]);
            acc[2][3] = fmaf(a.z, b.w, acc[2][3]);
            acc[3][0] = fmaf(a.w, b.x, acc[3][0]);
            acc[3][1] = fmaf(a.w, b.y, acc[3][1]);
            acc[3][2] = fmaf(a.w, b.z, acc[3][2]);
            acc[3][3] = fmaf(a.w, b.w, acc[3][3]);
        }
    }
    #pragma unroll
    for (int i = 0; i < 4; ++i) {
        int m = m0 + tm * 4 + i;
        #pragma unroll
        for (int j = 0; j < 4; ++j) {
            int nn = n0 + tn * 4 + j;
            if (nn < N) C[(size_t)m * N + nn] = acc[i][j];
        }
    }
}

// ---------------------------------------------------------------------------
// K3: dt = softplus(dt_raw + dt_bias)    [B*L, 256]
// ---------------------------------------------------------------------------
__global__ __launch_bounds__(256) void dt_kernel(
    const float* __restrict__ zx, const float* __restrict__ dt_bias,
    float* __restrict__ dtb)
{
    int idx = blockIdx.x * 256 + threadIdx.x;
    int h  = idx & 255;
    int bl = idx >> 8;
    float v = zx[(size_t)bl * D_IN_PROJ + (D_INNER + CONV_DIM) + h] + dt_bias[h];
    float sp = (v > 20.f) ? v : log1pf(expf(v));
    dtb[idx] = sp;
}

// ---------------------------------------------------------------------------
// K4: causal depthwise conv (kernel 4) + bias + SiLU  -> xBCs[b][l][c]
// ---------------------------------------------------------------------------
__global__ __launch_bounds__(256) void dwconv_kernel(
    const float* __restrict__ zx, const float* __restrict__ w,
    const float* __restrict__ bias, float* __restrict__ xBCs)
{
    int idx = blockIdx.x * 256 + threadIdx.x;
    int c  = idx % CONV_DIM;
    int bl = idx / CONV_DIM;
    int b = bl / L_, l = bl % L_;
    float4 wv = *(const float4*)&w[c * 4];
    float acc = bias[c];
    const float* base = zx + (size_t)(b * L_) * D_IN_PROJ + D_INNER + c;
    if (l - 3 >= 0) acc = fmaf(base[(size_t)(l - 3) * D_IN_PROJ], wv.x, acc);
    if (l - 2 >= 0) acc = fmaf(base[(size_t)(l - 2) * D_IN_PROJ], wv.y, acc);
    if (l - 1 >= 0) acc = fmaf(base[(size_t)(l - 1) * D_IN_PROJ], wv.z, acc);
    acc = fmaf(base[(size_t)l * D_IN_PROJ], wv.w, acc);
    float s = acc / (1.f + expf(-acc));
    xBCs[idx] = s;
}

// ---------------------------------------------------------------------------
// K5g: G[i][j] = C_i . B_j  per (b,chunk).  One block per (b,c). 2MB total.
// ---------------------------------------------------------------------------
__global__ __launch_bounds__(256) void gmat_kernel(
    const float* __restrict__ xBCs, float* __restrict__ G)
{
    __shared__ float Bs[64][16];
    __shared__ float Cs[64][16];
    int c = blockIdx.x & 31, b = blockIdx.x >> 5;
    int t = threadIdx.x;
    int row0 = b * L_ + c * SCAN_CL;
    {
        int j = t >> 2, q = t & 3;
        const float* r = xBCs + (size_t)(row0 + j) * CONV_DIM + D_INNER;
        *(float4*)&Bs[j][q * 4] = *(const float4*)(r + q * 4);
        *(float4*)&Cs[j][q * 4] = *(const float4*)(r + D_STATE + q * 4);
    }
    __syncthreads();
    int i = t >> 2, jq = t & 3;
    float4 c0 = *(const float4*)&Cs[i][0];
    float4 c1 = *(const float4*)&Cs[i][4];
    float4 c2 = *(const float4*)&Cs[i][8];
    float4 c3 = *(const float4*)&Cs[i][12];
    float dot[16];
    #pragma unroll
    for (int jj = 0; jj < 16; ++jj) {
        int j = jq * 16 + jj;
        float4 b0 = *(const float4*)&Bs[j][0];
        float4 b1 = *(const float4*)&Bs[j][4];
        float4 b2 = *(const float4*)&Bs[j][8];
        float4 b3 = *(const float4*)&Bs[j][12];
        float d = c0.x * b0.x + c0.y * b0.y + c0.z * b0.z + c0.w * b0.w;
        d = fmaf(c1.x, b1.x, d); d = fmaf(c1.y, b1.y, d);
        d = fmaf(c1.z, b1.z, d); d = fmaf(c1.w, b1.w, d);
        d = fmaf(c2.x, b2.x, d); d = fmaf(c2.y, b2.y, d);
        d = fmaf(c2.z, b2.z, d); d = fmaf(c2.w, b2.w, d);
        d = fmaf(c3.x, b3.x, d); d = fmaf(c3.y, b3.y, d);
        d = fmaf(c3.z, b3.z, d); d = fmaf(c3.w, b3.w, d);
        dot[jj] = d;
    }
    float* gout = G + ((size_t)blockIdx.x * 64 + i) * 64 + jq * 16;
    #pragma unroll
    for (int q = 0; q < 4; ++q)
        *(float4*)(gout + q * 4) = make_float4(dot[q*4], dot[q*4+1], dot[q*4+2], dot[q*4+3]);
}

// ---------------------------------------------------------------------------
// K5a: chunk-local state build as weighted matmul.
// Sloc[p][n] = sum_j exp(cum63-cum_j)*dt_j*x_j[p]*B_j[n];  prodA = exp(cum63)
// Block = (b, c, 4 heads); one wave per head.
// ---------------------------------------------------------------------------
__global__ __launch_bounds__(256) void scan_local2(
    const float* __restrict__ xBCs, const float* __restrict__ dtb,
    const float* __restrict__ A_log,
    float* __restrict__ Sloc, float* __restrict__ prodA)
{
    __shared__ float  BsT[16][68];          // transposed B tile (padded)
    __shared__ float4 Pk[4][64];            // {dt*x0, dt*x1, dt*x2, dt}
    __shared__ float  UT[4][3][64];         // weighted u[p][j] per head
    int bid = blockIdx.x;
    int hq = bid & 63, c = (bid >> 6) & 31, b = bid >> 11;
    int h0 = hq * 4;
    int t = threadIdx.x;
    int row0 = b * L_ + c * SCAN_CL;

    {   // staging (coalesced)
        int j = t >> 2, q = t & 3;
        const float* r = xBCs + (size_t)(row0 + j) * CONV_DIM;
        float4 bv = *(const float4*)(r + D_INNER + q * 4);
        BsT[q*4+0][j] = bv.x; BsT[q*4+1][j] = bv.y;
        BsT[q*4+2][j] = bv.z; BsT[q*4+3][j] = bv.w;
        float dtv = dtb[(size_t)(row0 + j) * NHEADS + h0 + q];
        const float* xr = r + (h0 + q) * 3;
        Pk[q][j] = make_float4(dtv * xr[0], dtv * xr[1], dtv * xr[2], dtv);
    }
    __syncthreads();

    int wv = t >> 6, lane = t & 63;
    int h = h0 + wv;
    float4 pk = Pk[wv][lane];
    float A = -__expf(A_log[h]);
    float cum = pk.w * A;
    #pragma unroll
    for (int off = 1; off < 64; off <<= 1) {
        float s = __shfl_up(cum, off);
        if (lane >= off) cum += s;
    }
    float cum63 = __shfl(cum, 63);
    float wf = __expf(cum63 - cum);         // <= 1, safe
    UT[wv][0][lane] = wf * pk.x;
    UT[wv][1][lane] = wf * pk.y;
    UT[wv][2][lane] = wf * pk.z;
    __syncthreads();

    int p = lane >> 4, n = lane & 15;
    int pc = (p < 3) ? p : 2;
    float state = 0.f;
    #pragma unroll
    for (int q = 0; q < 16; ++q) {
        float4 Bv = *(const float4*)&BsT[n][q * 4];
        float4 Uv = *(const float4*)&UT[wv][pc][q * 4];
        state = fmaf(Uv.x, Bv.x, state);
        state = fmaf(Uv.y, Bv.y, state);
        state = fmaf(Uv.z, Bv.z, state);
        state = fmaf(Uv.w, Bv.w, state);
    }
    size_t bh = (size_t)(b * NHEADS + h);
    if (p < 3) Sloc[(bh * SCAN_NC + c) * 48 + p * 16 + n] = state;
    if (lane == 0) prodA[bh * SCAN_NC + c] = __expf(cum63);
}

// ---------------------------------------------------------------------------
// K5b: sequential prefix over chunks, in place on Sloc (unchanged).
// ---------------------------------------------------------------------------
__global__ __launch_bounds__(256) void scan_prefix_kernel(
    float* __restrict__ Sloc, const float* __restrict__ prodA)
{
    int wv   = blockIdx.x * 4 + (threadIdx.x >> 6);
    int lane = threadIdx.x & 63;
    int p = lane >> 4, n = lane & 15;
    bool act = (p < 3);
    int l48 = ((p < 3) ? p : 2) * 16 + n;
    size_t base = (size_t)wv * SCAN_NC;

    float cur = 0.f;
    for (int c = 0; c < SCAN_NC; ++c) {
        float s  = Sloc[(base + c) * 48 + l48];
        float pa = prodA[base + c];
        if (act) Sloc[(base + c) * 48 + l48] = cur;
        cur = fmaf(pa, cur, s);
    }
}

// ---------------------------------------------------------------------------
// K5c: chunk-matmul final scan.
// y_i[p] = ri*sum_{J<I} S_IJ*(G_IJ @ xw_J) + diag + exp(cum_i)*(C_i.Hin) + D*x
// One wave per head (lane = row i); 4 heads/block.
// ---------------------------------------------------------------------------
__global__ __launch_bounds__(256) void scan_final2(
    const float* __restrict__ xBCs, const float* __restrict__ dtb,
    const float* __restrict__ A_log, const float* __restrict__ Dp,
    const float* __restrict__ Sinit, const float* __restrict__ G,
    float* __restrict__ y)
{
    __shared__ float4 Pk[4][64];            // {dt*x0,dt*x1,dt*x2, dt} -> .w := cum
    __shared__ float4 XW[4][64];            // {xw0,xw1,xw2, -}
    __shared__ float  Sin[4][48];
    __shared__ float  ys[4][64][3];
    int bid = blockIdx.x;
    int hq = bid & 63, c = (bid >> 6) & 31, b = bid >> 11;
    int h0 = hq * 4;
    int t = threadIdx.x;
    int row0 = b * L_ + c * SCAN_CL;

    {   // staging
        int j = t >> 2, q = t & 3;
        const float* r = xBCs + (size_t)(row0 + j) * CONV_DIM;
        float dtv = dtb[(size_t)(row0 + j) * NHEADS + h0 + q];
        const float* xr = r + (h0 + q) * 3;
        Pk[q][j] = make_float4(dtv * xr[0], dtv * xr[1], dtv * xr[2], dtv);
        if (t < 192) {
            int w2 = t / 48, k = t % 48;
            Sin[w2][k] = Sinit[((size_t)(b * NHEADS + h0 + w2) * SCAN_NC + c) * 48 + k];
        }
    }
    __syncthreads();

    int wv = t >> 6, lane = t & 63;
    int h = h0 + wv;
    int I = lane >> 4;
    float4 pk = Pk[wv][lane];               // keep dt in register before overwrite
    float A = -__expf(A_log[h]);
    float cum = pk.w * A;
    #pragma unroll
    for (int off = 1; off < 64; off <<= 1) {
        float s = __shfl_up(cum, off);
        if (lane >= off) cum += s;
    }
    float e0 = __shfl(cum, 15);
    float e1 = __shfl(cum, 31);
    float e2 = __shfl(cum, 47);
    float e3 = __shfl(cum, 63);
    int ia = (I << 4) - 1;
    float AIr = __shfl(cum, ia < 0 ? 0 : ia);
    float AI = (I == 0) ? 0.f : AIr;
    float ri = __expf(cum - AI);            // <=1
    float Eo = (I == 0) ? e0 : (I == 1) ? e1 : (I == 2) ? e2 : e3;
    float wj = __expf(Eo - cum);            // <=1 (lane as column j)
    XW[wv][lane] = make_float4(wj * pk.x, wj * pk.y, wj * pk.z, 0.f);
    Pk[wv][lane].w = cum;                   // publish cum_j for diag phase
    float S0 = (I > 0) ? __expf(AI - e0) : 0.f;
    float S1 = (I > 1) ? __expf(AI - e1) : 0.f;
    float S2 = (I > 2) ? __expf(AI - e2) : 0.f;
    float ecum = __expf(cum);
    __syncthreads();

    // ---- matmul phase: lane = row i ----
    const float* Grow = G + ((size_t)(b * SCAN_NC + c) * 64 + lane) * 64;

    float acc0 = 0.f, acc1 = 0.f, acc2 = 0.f;     // off-diagonal tiles
    #pragma unroll
    for (int J = 0; J < 3; ++J) {
        float SJ = (J == 0) ? S0 : (J == 1) ? S1 : S2;
        float t0 = 0.f, t1 = 0.f, t2 = 0.f;
        #pragma unroll
        for (int q = 0; q < 4; ++q) {
            float4 Gv = *(const float4*)(Grow + J * 16 + q * 4);
            #pragma unroll
            for (int k = 0; k < 4; ++k) {
                float gk = (k == 0) ? Gv.x : (k == 1) ? Gv.y : (k == 2) ? Gv.z : Gv.w;
                float4 u = XW[wv][J * 16 + q * 4 + k];
                t0 = fmaf(gk, u.x, t0);
                t1 = fmaf(gk, u.y, t1);
                t2 = fmaf(gk, u.z, t2);
            }
        }
        acc0 = fmaf(SJ, t0, acc0);
        acc1 = fmaf(SJ, t1, acc1);
        acc2 = fmaf(SJ, t2, acc2);
    }

    float d0 = 0.f, d1 = 0.f, d2 = 0.f;           // diagonal tile, per-elem exp
    #pragma unroll
    for (int q = 0; q < 4; ++q) {
        float4 Gv = *(const float4*)(Grow + (I << 4) + q * 4);
        #pragma unroll
        for (int k = 0; k < 4; ++k) {
            int j = (I << 4) + q * 4 + k;
            float gk = (k == 0) ? Gv.x : (k == 1) ? Gv.y : (k == 2) ? Gv.z : Gv.w;
            float4 pd = Pk[wv][j];                // {xd, cum_j}
            float e = __expf(cum - pd.w);         // arg<=0 when j<=i
            float m = (j <= lane) ? e : 0.f;      // select BEFORE multiply (inf-safe)
            float mg = m * gk;
            d0 = fmaf(mg, pd.x, d0);
            d1 = fmaf(mg, pd.y, d1);
            d2 = fmaf(mg, pd.z, d2);
        }
    }

    // inter-chunk: exp(cum_i) * C_i . Hin
    const float* Crow = xBCs + (size_t)(row0 + lane) * CONV_DIM + D_INNER + D_STATE;
    float s0 = 0.f, s1 = 0.f, s2 = 0.f;
    #pragma unroll
    for (int q = 0; q < 4; ++q) {
        float4 Cv = *(const float4*)(Crow + q * 4);
        float4 Sv0 = *(const float4*)&Sin[wv][ 0 + q * 4];
        float4 Sv1 = *(const float4*)&Sin[wv][16 + q * 4];
        float4 Sv2 = *(const float4*)&Sin[wv][32 + q * 4];
        s0 = fmaf(Cv.x, Sv0.x, s0); s0 = fmaf(Cv.y, Sv0.y, s0);
        s0 = fmaf(Cv.z, Sv0.z, s0); s0 = fmaf(Cv.w, Sv0.w, s0);
        s1 = fmaf(Cv.x, Sv1.x, s1); s1 = fmaf(Cv.y, Sv1.y, s1);
        s1 = fmaf(Cv.z, Sv1.z, s1); s1 = fmaf(Cv.w, Sv1.w, s1);
        s2 = fmaf(Cv.x, Sv2.x, s2); s2 = fmaf(Cv.y, Sv2.y, s2);
        s2 = fmaf(Cv.z, Sv2.z, s2); s2 = fmaf(Cv.w, Sv2.w, s2);
    }

    float rdt = 1.0f / pk.w;                       // recover x = xd/dt
    float Dh = Dp[h];
    float y0 = fmaf(ri, acc0, d0) + fmaf(ecum, s0, Dh * (pk.x * rdt));
    float y1 = fmaf(ri, acc1, d1) + fmaf(ecum, s1, Dh * (pk.y * rdt));
    float y2 = fmaf(ri, acc2, d2) + fmaf(ecum, s2, Dh * (pk.z * rdt));
    ys[wv][lane][0] = y0;
    ys[wv][lane][1] = y1;
    ys[wv][lane][2] = y2;
    __syncthreads();

    {   // coalesced epilogue
        int i2 = t >> 2, q2 = t & 3;
        float* dst = y + (size_t)(row0 + i2) * D_INNER + (size_t)(h0 + q2) * 3;
        dst[0] = ys[q2][i2][0];
        dst[1] = ys[q2][i2][1];
        dst[2] = ys[q2][i2][2];
    }
}

// ---------------------------------------------------------------------------
// K6: y = y * silu(z); RMSNorm over 768; * norm_w.   In-place on y.
// ---------------------------------------------------------------------------
__global__ __launch_bounds__(256) void gate_norm_kernel(
    const float* __restrict__ zx, const float* __restrict__ norm_w,
    float* __restrict__ y)
{
    int bl = blockIdx.x;
    int t  = threadIdx.x;
    const float* zrow = zx + (size_t)bl * D_IN_PROJ;
    float* yrow = y + (size_t)bl * D_INNER;

    float v[3];
    float ss = 0.f;
    #pragma unroll
    for (int j = 0; j < 3; ++j) {
        int i = t + j * 256;
        float z = zrow[i];
        float s = z / (1.f + expf(-z));
        float val = yrow[i] * s;
        v[j] = val;
        ss += val * val;
    }
    ss += __shfl_xor(ss, 32);
    ss += __shfl_xor(ss, 16);
    ss += __shfl_xor(ss, 8);
    ss += __shfl_xor(ss, 4);
    ss += __shfl_xor(ss, 2);
    ss += __shfl_xor(ss, 1);
    __shared__ float red[4];
    int lane = t & 63, wid = t >> 6;
    if (lane == 0) red[wid] = ss;
    __syncthreads();
    float tot = red[0] + red[1] + red[2] + red[3];
    float rs = rsqrtf(tot * (1.f / D_INNER) + 1e-5f);
    #pragma unroll
    for (int j = 0; j < 3; ++j) {
        int i = t + j * 256;
        yrow[i] = v[j] * rs * norm_w[i];
    }
}

// ---------------------------------------------------------------------------
// K8: output conv (kernel 4, pad (1,2)) with transpose
// ---------------------------------------------------------------------------
__global__ __launch_bounds__(128) void conv_out_kernel(
    const float* __restrict__ tmp, const float* __restrict__ w,
    float* __restrict__ out)
{
    __shared__ float ts[19][D_MODEL];
    int b  = blockIdx.x >> 7;
    int lt = blockIdx.x & 127;
    int l0 = lt * 16;
    int t  = threadIdx.x;

    const float* tb = tmp + (size_t)(b * L_) * D_MODEL;
    for (int idx = t; idx < 19 * D_MODEL; idx += 128) {
        int j = idx >> 8, c = idx & 255;
        int l = l0 - 1 + j;
        ts[j][c] = (l >= 0 && l < L_) ? tb[(size_t)l * D_MODEL + c] : 0.f;
    }
    __syncthreads();

    float acc[16];
    #pragma unroll
    for (int dl = 0; dl < 16; ++dl) acc[dl] = 0.f;

    const float4* wo = (const float4*)(w + (size_t)t * (D_MODEL * 4));
    for (int c = 0; c < D_MODEL; ++c) {
        float4 wv = wo[c];
        float r[19];
        #pragma unroll
        for (int j = 0; j < 19; ++j) r[j] = ts[j][c];
        #pragma unroll
        for (int dl = 0; dl < 16; ++dl) {
            acc[dl] = fmaf(r[dl + 0], wv.x, acc[dl]);
            acc[dl] = fmaf(r[dl + 1], wv.y, acc[dl]);
            acc[dl] = fmaf(r[dl + 2], wv.z, acc[dl]);
            acc[dl] = fmaf(r[dl + 3], wv.w, acc[dl]);
        }
    }
    float* ob = out + ((size_t)b * OUT_DIM + t) * L_ + l0;
    #pragma unroll
    for (int dl = 0; dl < 16; ++dl) ob[dl] = acc[dl];
}

// ---------------------------------------------------------------------------
extern "C" void kernel_launch(void* const* d_in, const int* in_sizes, int n_in,
                              void* d_out, int out_size, void* d_ws, size_t ws_size,
                              hipStream_t stream)
{
    const float* x           = (const float*)d_in[0];
    const float* conv_w      = (const float*)d_in[1];
    const float* conv_b      = (const float*)d_in[2];
    const float* in_proj_w   = (const float*)d_in[3];
    const float* dw_conv_w   = (const float*)d_in[4];
    const float* dw_conv_b   = (const float*)d_in[5];
    const float* dt_bias     = (const float*)d_in[6];
    const float* A_log       = (const float*)d_in[7];
    const float* Dp          = (const float*)d_in[8];
    const float* norm_w      = (const float*)d_in[9];
    const float* mamba_out_w = (const float*)d_in[10];
    const float* out_conv_w  = (const float*)d_in[11];
    float* out = (float*)d_out;
    float* ws  = (float*)d_ws;

    // workspace layout (floats) — total 31,981,568 floats (~128 MB), unchanged
    float* u    = ws;                        // 2,097,152
    float* zx   = u    + 2097152;            // 14,942,208
    float* xBCs = zx   + 14942208;           // 6,553,600
    float* dtb  = xBCs + 6553600;            // 2,097,152
    float* ybuf = dtb  + 2097152;            // 6,291,456
    // u is dead after gemm1; reuse: Gbuf (524,288) + Sloc (1,572,864) = exactly u
    float* Gbuf  = u;
    float* Sloc  = u + 524288;
    // prodA (32,768) aliases the start of ybuf: written by scan_local2, read by
    // prefix, dead before scan_final2 writes ybuf.
    float* prodA = ybuf;
    float* tmp2  = u;                        // gemm2 out (G/Sloc dead by then)

    conv_in_kernel<<<B_ * (L_ / 16), 256, 0, stream>>>(x, conv_w, conv_b, u);

    gemm_f32_kernel<<<dim3((D_IN_PROJ + 63) / 64, (B_ * L_) / 64), 256, 0, stream>>>(
        u, in_proj_w, zx, B_ * L_, D_IN_PROJ, D_MODEL);

    dt_kernel<<<(B_ * L_ * NHEADS) / 256, 256, 0, stream>>>(zx, dt_bias, dtb);

    dwconv_kernel<<<(B_ * L_ * CONV_DIM) / 256, 256, 0, stream>>>(
        zx, dw_conv_w, dw_conv_b, xBCs);

    gmat_kernel<<<B_ * SCAN_NC, 256, 0, stream>>>(xBCs, Gbuf);

    scan_local2<<<B_ * SCAN_NC * (NHEADS / 4), 256, 0, stream>>>(
        xBCs, dtb, A_log, Sloc, prodA);
    scan_prefix_kernel<<<(B_ * NHEADS) / 4, 256, 0, stream>>>(Sloc, prodA);
    scan_final2<<<B_ * SCAN_NC * (NHEADS / 4), 256, 0, stream>>>(
        xBCs, dtb, A_log, Dp, Sloc, Gbuf, ybuf);

    gate_norm_kernel<<<B_ * L_, 256, 0, stream>>>(zx, norm_w, ybuf);

    gemm_f32_kernel<<<dim3(D_MODEL / 64, (B_ * L_) / 64), 256, 0, stream>>>(
        ybuf, mamba_out_w, tmp2, B_ * L_, D_MODEL, D_INNER);

    conv_out_kernel<<<B_ * (L_ / 16), 128, 0, stream>>>(tmp2, out_conv_w, out);
}

// Round 4
// 484.276 us; speedup vs baseline: 1.7021x; 1.1564x over previous
//
#include <hip/hip_runtime.h>
#include <math.h>

#define B_      4
#define L_      2048
#define IN_DIM  128
#define D_MODEL 256
#define OUT_DIM 128
#define D_STATE 16
#define D_INNER 768
#define NHEADS  256
#define HEADDIM 3
#define CONV_DIM 800
#define D_IN_PROJ 1824

#define SCAN_NC 32
#define SCAN_CL 64

typedef short  short8 __attribute__((ext_vector_type(8)));
typedef float  f32x4  __attribute__((ext_vector_type(4)));

__device__ __forceinline__ unsigned short f2bf(float f) {
    unsigned int u = __float_as_uint(f);
    u = (u + 0x7fffu + ((u >> 16) & 1u)) >> 16;     // RN-to-even
    return (unsigned short)u;
}
__device__ __forceinline__ float bf2f(unsigned short h) {
    return __uint_as_float(((unsigned int)h) << 16);
}

// ---------------------------------------------------------------------------
// K1: input conv (kernel 4, pad (1,2)) fused with transpose -> u[b][l][o]
// ---------------------------------------------------------------------------
__global__ __launch_bounds__(256) void conv_in_kernel(
    const float* __restrict__ x, const float* __restrict__ w,
    const float* __restrict__ bias, float* __restrict__ u)
{
    __shared__ float xs[IN_DIM][19];
    int b  = blockIdx.x >> 7;
    int lt = blockIdx.x & 127;
    int l0 = lt * 16;
    int t  = threadIdx.x;

    const float* xb = x + (size_t)b * IN_DIM * L_;
    for (int idx = t; idx < IN_DIM * 19; idx += 256) {
        int i = idx / 19, j = idx % 19;
        int l = l0 - 1 + j;
        xs[i][j] = (l >= 0 && l < L_) ? xb[(size_t)i * L_ + l] : 0.f;
    }
    __syncthreads();

    float acc[16];
    float bo = bias[t];
    #pragma unroll
    for (int dl = 0; dl < 16; ++dl) acc[dl] = bo;

    const float4* wo = (const float4*)(w + (size_t)t * (IN_DIM * 4));
    for (int i = 0; i < IN_DIM; ++i) {
        float4 wv = wo[i];
        float r[19];
        #pragma unroll
        for (int j = 0; j < 19; ++j) r[j] = xs[i][j];
        #pragma unroll
        for (int dl = 0; dl < 16; ++dl) {
            acc[dl] = fmaf(r[dl + 0], wv.x, acc[dl]);
            acc[dl] = fmaf(r[dl + 1], wv.y, acc[dl]);
            acc[dl] = fmaf(r[dl + 2], wv.z, acc[dl]);
            acc[dl] = fmaf(r[dl + 3], wv.w, acc[dl]);
        }
    }
    float* ub = u + ((size_t)(b * L_ + l0)) * D_MODEL + t;
    #pragma unroll
    for (int dl = 0; dl < 16; ++dl) ub[(size_t)dl * D_MODEL] = acc[dl];
}

// ---------------------------------------------------------------------------
// split fp32 -> (hi, lo) bf16 elementwise
// ---------------------------------------------------------------------------
__global__ __launch_bounds__(256) void split_kernel(
    const float* __restrict__ src, unsigned short* __restrict__ hi,
    unsigned short* __restrict__ lo, int n)
{
    int i = blockIdx.x * 256 + threadIdx.x;
    if (i < n) {
        float v = src[i];
        unsigned short h = f2bf(v);
        hi[i] = h;
        lo[i] = f2bf(v - bf2f(h));
    }
}

// ---------------------------------------------------------------------------
// transpose + split: src[K][N] fp32 -> dh/dl [N][K] bf16
// grid (N/32, K/32), 256 threads
// ---------------------------------------------------------------------------
__global__ __launch_bounds__(256) void tconv_kernel(
    const float* __restrict__ src, unsigned short* __restrict__ dh,
    unsigned short* __restrict__ dl, int K, int N)
{
    __shared__ float tile[32][33];
    int k0 = blockIdx.y * 32, n0 = blockIdx.x * 32;
    int tx = threadIdx.x & 31, ty = threadIdx.x >> 5;   // ty 0..7
    #pragma unroll
    for (int r = 0; r < 4; ++r)
        tile[ty + r * 8][tx] = src[(size_t)(k0 + ty + r * 8) * N + n0 + tx];
    __syncthreads();
    #pragma unroll
    for (int r = 0; r < 4; ++r) {
        int n = n0 + ty + r * 8;
        float v = tile[tx][ty + r * 8];
        unsigned short h = f2bf(v);
        dh[(size_t)n * K + k0 + tx] = h;
        dl[(size_t)n * K + k0 + tx] = f2bf(v - bf2f(h));
    }
}

// ---------------------------------------------------------------------------
// K2: split-bf16 MFMA GEMM.  C[M,N] = (Ah+Al)[M,K] * (Bh+Bl)^T  (B is [N][K])
// 128x128 tile, 4 waves (2x2 of 64x64), 16x16x32 bf16 MFMA, 3-product split.
// M%128==0, K%32==0; N guarded.
// ---------------------------------------------------------------------------
__global__ __launch_bounds__(256) void gemm_bf16s_kernel(
    const unsigned short* __restrict__ Ah, const unsigned short* __restrict__ Al,
    const unsigned short* __restrict__ Bh, const unsigned short* __restrict__ Bl,
    float* __restrict__ C, int M, int N, int K)
{
    __shared__ __align__(16) unsigned short AsH[128][40];
    __shared__ __align__(16) unsigned short AsL[128][40];
    __shared__ __align__(16) unsigned short BsH[128][40];
    __shared__ __align__(16) unsigned short BsL[128][40];

    int m0 = blockIdx.y * 128, n0 = blockIdx.x * 128;
    int t = threadIdx.x;
    int wid = t >> 6, lane = t & 63;
    int wm = (wid >> 1) * 64, wn = (wid & 1) * 64;
    int fr = lane & 15;          // frag row/col within 16
    int fq = lane >> 4;          // quad 0..3

    f32x4 z4 = {0.f, 0.f, 0.f, 0.f};
    f32x4 acc[4][4];
    #pragma unroll
    for (int i = 0; i < 4; ++i)
        #pragma unroll
        for (int j = 0; j < 4; ++j) acc[i][j] = z4;

    for (int k0 = 0; k0 < K; k0 += 32) {
        __syncthreads();
        #pragma unroll
        for (int p = 0; p < 2; ++p) {
            int idx = p * 256 + t;
            int row = idx >> 2, q = idx & 3;
            int koff = k0 + q * 8;
            *(float4*)&AsH[row][q * 8] =
                *(const float4*)(Ah + (size_t)(m0 + row) * K + koff);
            *(float4*)&AsL[row][q * 8] =
                *(const float4*)(Al + (size_t)(m0 + row) * K + koff);
            int n = n0 + row;
            float4 vbh = make_float4(0.f, 0.f, 0.f, 0.f), vbl = vbh;
            if (n < N) {
                vbh = *(const float4*)(Bh + (size_t)n * K + koff);
                vbl = *(const float4*)(Bl + (size_t)n * K + koff);
            }
            *(float4*)&BsH[row][q * 8] = vbh;
            *(float4*)&BsL[row][q * 8] = vbl;
        }
        __syncthreads();

        short8 ah[4], al[4], bh[4], bl[4];
        #pragma unroll
        for (int i = 0; i < 4; ++i) {
            ah[i] = *(const short8*)&AsH[wm + i * 16 + fr][fq * 8];
            al[i] = *(const short8*)&AsL[wm + i * 16 + fr][fq * 8];
            bh[i] = *(const short8*)&BsH[wn + i * 16 + fr][fq * 8];
            bl[i] = *(const short8*)&BsL[wn + i * 16 + fr][fq * 8];
        }
        #pragma unroll
        for (int i = 0; i < 4; ++i)
            #pragma unroll
            for (int j = 0; j < 4; ++j) {
                acc[i][j] = __builtin_amdgcn_mfma_f32_16x16x32_bf16(
                    ah[i], bh[j], acc[i][j], 0, 0, 0);
                acc[i][j] = __builtin_amdgcn_mfma_f32_16x16x32_bf16(
                    ah[i], bl[j], acc[i][j], 0, 0, 0);
                acc[i][j] = __builtin_amdgcn_mfma_f32_16x16x32_bf16(
                    al[i], bh[j], acc[i][j], 0, 0, 0);
            }
    }

    #pragma unroll
    for (int i = 0; i < 4; ++i) {
        int r0 = m0 + wm + i * 16 + fq * 4;
        #pragma unroll
        for (int j = 0; j < 4; ++j) {
            int cc = n0 + wn + j * 16 + fr;
            if (cc < N) {
                #pragma unroll
                for (int r = 0; r < 4; ++r)
                    C[(size_t)(r0 + r) * N + cc] = acc[i][j][r];
            }
        }
    }
}

// ---------------------------------------------------------------------------
// K3: dt = softplus(dt_raw + dt_bias)    [B*L, 256]
// ---------------------------------------------------------------------------
__global__ __launch_bounds__(256) void dt_kernel(
    const float* __restrict__ zx, const float* __restrict__ dt_bias,
    float* __restrict__ dtb)
{
    int idx = blockIdx.x * 256 + threadIdx.x;
    int h  = idx & 255;
    int bl = idx >> 8;
    float v = zx[(size_t)bl * D_IN_PROJ + (D_INNER + CONV_DIM) + h] + dt_bias[h];
    float sp = (v > 20.f) ? v : log1pf(expf(v));
    dtb[idx] = sp;
}

// ---------------------------------------------------------------------------
// K4: causal depthwise conv (kernel 4) + bias + SiLU  -> xBCs[b][l][c]
// ---------------------------------------------------------------------------
__global__ __launch_bounds__(256) void dwconv_kernel(
    const float* __restrict__ zx, const float* __restrict__ w,
    const float* __restrict__ bias, float* __restrict__ xBCs)
{
    int idx = blockIdx.x * 256 + threadIdx.x;
    int c  = idx % CONV_DIM;
    int bl = idx / CONV_DIM;
    int b = bl / L_, l = bl % L_;
    float4 wv = *(const float4*)&w[c * 4];
    float acc = bias[c];
    const float* base = zx + (size_t)(b * L_) * D_IN_PROJ + D_INNER + c;
    if (l - 3 >= 0) acc = fmaf(base[(size_t)(l - 3) * D_IN_PROJ], wv.x, acc);
    if (l - 2 >= 0) acc = fmaf(base[(size_t)(l - 2) * D_IN_PROJ], wv.y, acc);
    if (l - 1 >= 0) acc = fmaf(base[(size_t)(l - 1) * D_IN_PROJ], wv.z, acc);
    acc = fmaf(base[(size_t)l * D_IN_PROJ], wv.w, acc);
    float s = acc / (1.f + expf(-acc));
    xBCs[idx] = s;
}

// ---------------------------------------------------------------------------
// K5g: G[i][j] = C_i . B_j  per (b,chunk)
// ---------------------------------------------------------------------------
__global__ __launch_bounds__(256) void gmat_kernel(
    const float* __restrict__ xBCs, float* __restrict__ G)
{
    __shared__ float Bs[64][16];
    __shared__ float Cs[64][16];
    int c = blockIdx.x & 31, b = blockIdx.x >> 5;
    int t = threadIdx.x;
    int row0 = b * L_ + c * SCAN_CL;
    {
        int j = t >> 2, q = t & 3;
        const float* r = xBCs + (size_t)(row0 + j) * CONV_DIM + D_INNER;
        *(float4*)&Bs[j][q * 4] = *(const float4*)(r + q * 4);
        *(float4*)&Cs[j][q * 4] = *(const float4*)(r + D_STATE + q * 4);
    }
    __syncthreads();
    int i = t >> 2, jq = t & 3;
    float4 c0 = *(const float4*)&Cs[i][0];
    float4 c1 = *(const float4*)&Cs[i][4];
    float4 c2 = *(const float4*)&Cs[i][8];
    float4 c3 = *(const float4*)&Cs[i][12];
    float dot[16];
    #pragma unroll
    for (int jj = 0; jj < 16; ++jj) {
        int j = jq * 16 + jj;
        float4 b0 = *(const float4*)&Bs[j][0];
        float4 b1 = *(const float4*)&Bs[j][4];
        float4 b2 = *(const float4*)&Bs[j][8];
        float4 b3 = *(const float4*)&Bs[j][12];
        float d = c0.x * b0.x + c0.y * b0.y + c0.z * b0.z + c0.w * b0.w;
        d = fmaf(c1.x, b1.x, d); d = fmaf(c1.y, b1.y, d);
        d = fmaf(c1.z, b1.z, d); d = fmaf(c1.w, b1.w, d);
        d = fmaf(c2.x, b2.x, d); d = fmaf(c2.y, b2.y, d);
        d = fmaf(c2.z, b2.z, d); d = fmaf(c2.w, b2.w, d);
        d = fmaf(c3.x, b3.x, d); d = fmaf(c3.y, b3.y, d);
        d = fmaf(c3.z, b3.z, d); d = fmaf(c3.w, b3.w, d);
        dot[jj] = d;
    }
    float* gout = G + ((size_t)blockIdx.x * 64 + i) * 64 + jq * 16;
    #pragma unroll
    for (int q = 0; q < 4; ++q)
        *(float4*)(gout + q * 4) = make_float4(dot[q*4], dot[q*4+1], dot[q*4+2], dot[q*4+3]);
}

// ---------------------------------------------------------------------------
// K5a: chunk-local state build as weighted matmul
// ---------------------------------------------------------------------------
__global__ __launch_bounds__(256) void scan_local2(
    const float* __restrict__ xBCs, const float* __restrict__ dtb,
    const float* __restrict__ A_log,
    float* __restrict__ Sloc, float* __restrict__ prodA)
{
    __shared__ float  BsT[16][68];
    __shared__ float4 Pk[4][64];
    __shared__ float  UT[4][3][64];
    int bid = blockIdx.x;
    int hq = bid & 63, c = (bid >> 6) & 31, b = bid >> 11;
    int h0 = hq * 4;
    int t = threadIdx.x;
    int row0 = b * L_ + c * SCAN_CL;

    {
        int j = t >> 2, q = t & 3;
        const float* r = xBCs + (size_t)(row0 + j) * CONV_DIM;
        float4 bv = *(const float4*)(r + D_INNER + q * 4);
        BsT[q*4+0][j] = bv.x; BsT[q*4+1][j] = bv.y;
        BsT[q*4+2][j] = bv.z; BsT[q*4+3][j] = bv.w;
        float dtv = dtb[(size_t)(row0 + j) * NHEADS + h0 + q];
        const float* xr = r + (h0 + q) * 3;
        Pk[q][j] = make_float4(dtv * xr[0], dtv * xr[1], dtv * xr[2], dtv);
    }
    __syncthreads();

    int wv = t >> 6, lane = t & 63;
    int h = h0 + wv;
    float4 pk = Pk[wv][lane];
    float A = -__expf(A_log[h]);
    float cum = pk.w * A;
    #pragma unroll
    for (int off = 1; off < 64; off <<= 1) {
        float s = __shfl_up(cum, off);
        if (lane >= off) cum += s;
    }
    float cum63 = __shfl(cum, 63);
    float wf = __expf(cum63 - cum);
    UT[wv][0][lane] = wf * pk.x;
    UT[wv][1][lane] = wf * pk.y;
    UT[wv][2][lane] = wf * pk.z;
    __syncthreads();

    int p = lane >> 4, n = lane & 15;
    int pc = (p < 3) ? p : 2;
    float state = 0.f;
    #pragma unroll
    for (int q = 0; q < 16; ++q) {
        float4 Bv = *(const float4*)&BsT[n][q * 4];
        float4 Uv = *(const float4*)&UT[wv][pc][q * 4];
        state = fmaf(Uv.x, Bv.x, state);
        state = fmaf(Uv.y, Bv.y, state);
        state = fmaf(Uv.z, Bv.z, state);
        state = fmaf(Uv.w, Bv.w, state);
    }
    size_t bh = (size_t)(b * NHEADS + h);
    if (p < 3) Sloc[(bh * SCAN_NC + c) * 48 + p * 16 + n] = state;
    if (lane == 0) prodA[bh * SCAN_NC + c] = __expf(cum63);
}

// ---------------------------------------------------------------------------
// K5b: sequential prefix over chunks, in place on Sloc
// ---------------------------------------------------------------------------
__global__ __launch_bounds__(256) void scan_prefix_kernel(
    float* __restrict__ Sloc, const float* __restrict__ prodA)
{
    int wv   = blockIdx.x * 4 + (threadIdx.x >> 6);
    int lane = threadIdx.x & 63;
    int p = lane >> 4, n = lane & 15;
    bool act = (p < 3);
    int l48 = ((p < 3) ? p : 2) * 16 + n;
    size_t base = (size_t)wv * SCAN_NC;

    float cur = 0.f;
    for (int c = 0; c < SCAN_NC; ++c) {
        float s  = Sloc[(base + c) * 48 + l48];
        float pa = prodA[base + c];
        if (act) Sloc[(base + c) * 48 + l48] = cur;
        cur = fmaf(pa, cur, s);
    }
}

// ---------------------------------------------------------------------------
// K5c: chunk-matmul final scan
// ---------------------------------------------------------------------------
__global__ __launch_bounds__(256) void scan_final2(
    const float* __restrict__ xBCs, const float* __restrict__ dtb,
    const float* __restrict__ A_log, const float* __restrict__ Dp,
    const float* __restrict__ Sinit, const float* __restrict__ G,
    float* __restrict__ y)
{
    __shared__ float4 Pk[4][64];
    __shared__ float4 XW[4][64];
    __shared__ float  Sin[4][48];
    __shared__ float  ys[4][64][3];
    int bid = blockIdx.x;
    int hq = bid & 63, c = (bid >> 6) & 31, b = bid >> 11;
    int h0 = hq * 4;
    int t = threadIdx.x;
    int row0 = b * L_ + c * SCAN_CL;

    {
        int j = t >> 2, q = t & 3;
        const float* r = xBCs + (size_t)(row0 + j) * CONV_DIM;
        float dtv = dtb[(size_t)(row0 + j) * NHEADS + h0 + q];
        const float* xr = r + (h0 + q) * 3;
        Pk[q][j] = make_float4(dtv * xr[0], dtv * xr[1], dtv * xr[2], dtv);
        if (t < 192) {
            int w2 = t / 48, k = t % 48;
            Sin[w2][k] = Sinit[((size_t)(b * NHEADS + h0 + w2) * SCAN_NC + c) * 48 + k];
        }
    }
    __syncthreads();

    int wv = t >> 6, lane = t & 63;
    int h = h0 + wv;
    int I = lane >> 4;
    float4 pk = Pk[wv][lane];
    float A = -__expf(A_log[h]);
    float cum = pk.w * A;
    #pragma unroll
    for (int off = 1; off < 64; off <<= 1) {
        float s = __shfl_up(cum, off);
        if (lane >= off) cum += s;
    }
    float e0 = __shfl(cum, 15);
    float e1 = __shfl(cum, 31);
    float e2 = __shfl(cum, 47);
    float e3 = __shfl(cum, 63);
    int ia = (I << 4) - 1;
    float AIr = __shfl(cum, ia < 0 ? 0 : ia);
    float AI = (I == 0) ? 0.f : AIr;
    float ri = __expf(cum - AI);
    float Eo = (I == 0) ? e0 : (I == 1) ? e1 : (I == 2) ? e2 : e3;
    float wj = __expf(Eo - cum);
    XW[wv][lane] = make_float4(wj * pk.x, wj * pk.y, wj * pk.z, 0.f);
    Pk[wv][lane].w = cum;
    float S0 = (I > 0) ? __expf(AI - e0) : 0.f;
    float S1 = (I > 1) ? __expf(AI - e1) : 0.f;
    float S2 = (I > 2) ? __expf(AI - e2) : 0.f;
    float ecum = __expf(cum);
    __syncthreads();

    const float* Grow = G + ((size_t)(b * SCAN_NC + c) * 64 + lane) * 64;

    float acc0 = 0.f, acc1 = 0.f, acc2 = 0.f;
    #pragma unroll
    for (int J = 0; J < 3; ++J) {
        float SJ = (J == 0) ? S0 : (J == 1) ? S1 : S2;
        float t0 = 0.f, t1 = 0.f, t2 = 0.f;
        #pragma unroll
        for (int q = 0; q < 4; ++q) {
            float4 Gv = *(const float4*)(Grow + J * 16 + q * 4);
            #pragma unroll
            for (int k = 0; k < 4; ++k) {
                float gk = (k == 0) ? Gv.x : (k == 1) ? Gv.y : (k == 2) ? Gv.z : Gv.w;
                float4 u = XW[wv][J * 16 + q * 4 + k];
                t0 = fmaf(gk, u.x, t0);
                t1 = fmaf(gk, u.y, t1);
                t2 = fmaf(gk, u.z, t2);
            }
        }
        acc0 = fmaf(SJ, t0, acc0);
        acc1 = fmaf(SJ, t1, acc1);
        acc2 = fmaf(SJ, t2, acc2);
    }

    float d0 = 0.f, d1 = 0.f, d2 = 0.f;
    #pragma unroll
    for (int q = 0; q < 4; ++q) {
        float4 Gv = *(const float4*)(Grow + (I << 4) + q * 4);
        #pragma unroll
        for (int k = 0; k < 4; ++k) {
            int j = (I << 4) + q * 4 + k;
            float gk = (k == 0) ? Gv.x : (k == 1) ? Gv.y : (k == 2) ? Gv.z : Gv.w;
            float4 pd = Pk[wv][j];
            float e = __expf(cum - pd.w);
            float m = (j <= lane) ? e : 0.f;
            float mg = m * gk;
            d0 = fmaf(mg, pd.x, d0);
            d1 = fmaf(mg, pd.y, d1);
            d2 = fmaf(mg, pd.z, d2);
        }
    }

    const float* Crow = xBCs + (size_t)(row0 + lane) * CONV_DIM + D_INNER + D_STATE;
    float s0 = 0.f, s1 = 0.f, s2 = 0.f;
    #pragma unroll
    for (int q = 0; q < 4; ++q) {
        float4 Cv = *(const float4*)(Crow + q * 4);
        float4 Sv0 = *(const float4*)&Sin[wv][ 0 + q * 4];
        float4 Sv1 = *(const float4*)&Sin[wv][16 + q * 4];
        float4 Sv2 = *(const float4*)&Sin[wv][32 + q * 4];
        s0 = fmaf(Cv.x, Sv0.x, s0); s0 = fmaf(Cv.y, Sv0.y, s0);
        s0 = fmaf(Cv.z, Sv0.z, s0); s0 = fmaf(Cv.w, Sv0.w, s0);
        s1 = fmaf(Cv.x, Sv1.x, s1); s1 = fmaf(Cv.y, Sv1.y, s1);
        s1 = fmaf(Cv.z, Sv1.z, s1); s1 = fmaf(Cv.w, Sv1.w, s1);
        s2 = fmaf(Cv.x, Sv2.x, s2); s2 = fmaf(Cv.y, Sv2.y, s2);
        s2 = fmaf(Cv.z, Sv2.z, s2); s2 = fmaf(Cv.w, Sv2.w, s2);
    }

    float rdt = 1.0f / pk.w;
    float Dh = Dp[h];
    float y0 = fmaf(ri, acc0, d0) + fmaf(ecum, s0, Dh * (pk.x * rdt));
    float y1 = fmaf(ri, acc1, d1) + fmaf(ecum, s1, Dh * (pk.y * rdt));
    float y2 = fmaf(ri, acc2, d2) + fmaf(ecum, s2, Dh * (pk.z * rdt));
    ys[wv][lane][0] = y0;
    ys[wv][lane][1] = y1;
    ys[wv][lane][2] = y2;
    __syncthreads();

    {
        int i2 = t >> 2, q2 = t & 3;
        float* dst = y + (size_t)(row0 + i2) * D_INNER + (size_t)(h0 + q2) * 3;
        dst[0] = ys[q2][i2][0];
        dst[1] = ys[q2][i2][1];
        dst[2] = ys[q2][i2][2];
    }
}

// ---------------------------------------------------------------------------
// K6: y = y * silu(z); RMSNorm over 768; * norm_w.  Writes split-bf16 output.
// ---------------------------------------------------------------------------
__global__ __launch_bounds__(256) void gate_norm_kernel(
    const float* __restrict__ zx, const float* __restrict__ norm_w,
    const float* __restrict__ y,
    unsigned short* __restrict__ yh, unsigned short* __restrict__ yl)
{
    int bl = blockIdx.x;
    int t  = threadIdx.x;
    const float* zrow = zx + (size_t)bl * D_IN_PROJ;
    const float* yrow = y + (size_t)bl * D_INNER;

    float v[3];
    float ss = 0.f;
    #pragma unroll
    for (int j = 0; j < 3; ++j) {
        int i = t + j * 256;
        float z = zrow[i];
        float s = z / (1.f + expf(-z));
        float val = yrow[i] * s;
        v[j] = val;
        ss += val * val;
    }
    ss += __shfl_xor(ss, 32);
    ss += __shfl_xor(ss, 16);
    ss += __shfl_xor(ss, 8);
    ss += __shfl_xor(ss, 4);
    ss += __shfl_xor(ss, 2);
    ss += __shfl_xor(ss, 1);
    __shared__ float red[4];
    int lane = t & 63, wid = t >> 6;
    if (lane == 0) red[wid] = ss;
    __syncthreads();
    float tot = red[0] + red[1] + red[2] + red[3];
    float rs = rsqrtf(tot * (1.f / D_INNER) + 1e-5f);
    #pragma unroll
    for (int j = 0; j < 3; ++j) {
        int i = t + j * 256;
        float o = v[j] * rs * norm_w[i];
        unsigned short h = f2bf(o);
        yh[(size_t)bl * D_INNER + i] = h;
        yl[(size_t)bl * D_INNER + i] = f2bf(o - bf2f(h));
    }
}

// ---------------------------------------------------------------------------
// K8: output conv (kernel 4, pad (1,2)) with transpose
// ---------------------------------------------------------------------------
__global__ __launch_bounds__(128) void conv_out_kernel(
    const float* __restrict__ tmp, const float* __restrict__ w,
    float* __restrict__ out)
{
    __shared__ float ts[19][D_MODEL];
    int b  = blockIdx.x >> 7;
    int lt = blockIdx.x & 127;
    int l0 = lt * 16;
    int t  = threadIdx.x;

    const float* tb = tmp + (size_t)(b * L_) * D_MODEL;
    for (int idx = t; idx < 19 * D_MODEL; idx += 128) {
        int j = idx >> 8, c = idx & 255;
        int l = l0 - 1 + j;
        ts[j][c] = (l >= 0 && l < L_) ? tb[(size_t)l * D_MODEL + c] : 0.f;
    }
    __syncthreads();

    float acc[16];
    #pragma unroll
    for (int dl = 0; dl < 16; ++dl) acc[dl] = 0.f;

    const float4* wo = (const float4*)(w + (size_t)t * (D_MODEL * 4));
    for (int c = 0; c < D_MODEL; ++c) {
        float4 wv = wo[c];
        float r[19];
        #pragma unroll
        for (int j = 0; j < 19; ++j) r[j] = ts[j][c];
        #pragma unroll
        for (int dl = 0; dl < 16; ++dl) {
            acc[dl] = fmaf(r[dl + 0], wv.x, acc[dl]);
            acc[dl] = fmaf(r[dl + 1], wv.y, acc[dl]);
            acc[dl] = fmaf(r[dl + 2], wv.z, acc[dl]);
            acc[dl] = fmaf(r[dl + 3], wv.w, acc[dl]);
        }
    }
    float* ob = out + ((size_t)b * OUT_DIM + t) * L_ + l0;
    #pragma unroll
    for (int dl = 0; dl < 16; ++dl) ob[dl] = acc[dl];
}

// ---------------------------------------------------------------------------
extern "C" void kernel_launch(void* const* d_in, const int* in_sizes, int n_in,
                              void* d_out, int out_size, void* d_ws, size_t ws_size,
                              hipStream_t stream)
{
    const float* x           = (const float*)d_in[0];
    const float* conv_w      = (const float*)d_in[1];
    const float* conv_b      = (const float*)d_in[2];
    const float* in_proj_w   = (const float*)d_in[3];
    const float* dw_conv_w   = (const float*)d_in[4];
    const float* dw_conv_b   = (const float*)d_in[5];
    const float* dt_bias     = (const float*)d_in[6];
    const float* A_log       = (const float*)d_in[7];
    const float* Dp          = (const float*)d_in[8];
    const float* norm_w      = (const float*)d_in[9];
    const float* mamba_out_w = (const float*)d_in[10];
    const float* out_conv_w  = (const float*)d_in[11];
    float* out = (float*)d_out;
    float* ws  = (float*)d_ws;

    // fp32 workspace regions (floats) — 31,981,568 total, unchanged footprint
    float* u    = ws;                        // 2,097,152
    float* zx   = u    + 2097152;            // 14,942,208
    float* xBCs = zx   + 14942208;           // 6,553,600
    float* dtb  = xBCs + 6553600;            // 2,097,152
    float* ybuf = dtb  + 2097152;            // 6,291,456

    // Aliased bf16 buffers (liveness-checked):
    // u region: Gbuf+Sloc during scans (u fp32 dead after split_kernel/gemm1)
    float* Gbuf  = u;                        // 524,288
    float* Sloc  = u + 524288;               // 1,572,864
    // prodA in ybuf[0..32K): live scan_local→prefix, before scan_final2 writes ybuf
    float* prodA = ybuf;
    // u_hi/u_lo in ybuf[32K..2.13M): live split→gemm1, dead before scan_final2
    unsigned short* u_hi = (unsigned short*)(ybuf + 32768);
    unsigned short* u_lo = (unsigned short*)(ybuf + 32768 + 1048576);
    // in_proj_w^T hi/lo in xBCs[0..467K): live tconv→gemm1, dead before dwconv
    unsigned short* ipw_hi = (unsigned short*)xBCs;
    unsigned short* ipw_lo = (unsigned short*)(xBCs + 233472);
    // yb hi/lo in xBCs (raw xBCs dead after scan_final2): live gate_norm→gemm2
    unsigned short* yb_hi = (unsigned short*)xBCs;
    unsigned short* yb_lo = (unsigned short*)(xBCs + 3145728);
    // mamba_out_w^T hi/lo in zx[2.1M..): written after gate_norm (zx dead)
    unsigned short* mow_hi = (unsigned short*)(zx + 2097152);
    unsigned short* mow_lo = (unsigned short*)(zx + 2195456);
    // gemm2 output in zx[0..2.1M) (zx dead after gate_norm)
    float* tmp2 = zx;

    // 1. input conv -> u [B,L,256] fp32
    conv_in_kernel<<<B_ * (L_ / 16), 256, 0, stream>>>(x, conv_w, conv_b, u);

    // 2. split u -> bf16 hi/lo; transpose+split in_proj_w -> [1824][256]
    split_kernel<<<(B_ * L_ * D_MODEL) / 256, 256, 0, stream>>>(
        u, u_hi, u_lo, B_ * L_ * D_MODEL);
    tconv_kernel<<<dim3(D_IN_PROJ / 32, D_MODEL / 32), 256, 0, stream>>>(
        in_proj_w, ipw_hi, ipw_lo, D_MODEL, D_IN_PROJ);

    // 3. in_proj GEMM (split-bf16 MFMA): zx[8192,1824]
    gemm_bf16s_kernel<<<dim3((D_IN_PROJ + 127) / 128, (B_ * L_) / 128), 256, 0, stream>>>(
        u_hi, u_lo, ipw_hi, ipw_lo, zx, B_ * L_, D_IN_PROJ, D_MODEL);

    // 4. dt = softplus(dt_raw + bias)
    dt_kernel<<<(B_ * L_ * NHEADS) / 256, 256, 0, stream>>>(zx, dt_bias, dtb);

    // 5. depthwise conv + silu -> xBCs [B,L,800] (overwrites dead ipw_t)
    dwconv_kernel<<<(B_ * L_ * CONV_DIM) / 256, 256, 0, stream>>>(
        zx, dw_conv_w, dw_conv_b, xBCs);

    // 6. chunked SSD scan -> ybuf [B,L,768]
    gmat_kernel<<<B_ * SCAN_NC, 256, 0, stream>>>(xBCs, Gbuf);
    scan_local2<<<B_ * SCAN_NC * (NHEADS / 4), 256, 0, stream>>>(
        xBCs, dtb, A_log, Sloc, prodA);
    scan_prefix_kernel<<<(B_ * NHEADS) / 4, 256, 0, stream>>>(Sloc, prodA);
    scan_final2<<<B_ * SCAN_NC * (NHEADS / 4), 256, 0, stream>>>(
        xBCs, dtb, A_log, Dp, Sloc, Gbuf, ybuf);

    // 7. gating + RMSNorm -> split-bf16 (into dead xBCs region)
    gate_norm_kernel<<<B_ * L_, 256, 0, stream>>>(zx, norm_w, ybuf, yb_hi, yb_lo);

    // 8. transpose+split mamba_out_w -> [256][768] (zx dead now)
    tconv_kernel<<<dim3(D_MODEL / 32, D_INNER / 32), 256, 0, stream>>>(
        mamba_out_w, mow_hi, mow_lo, D_INNER, D_MODEL);

    // 9. out GEMM (split-bf16 MFMA): tmp2[8192,256]
    gemm_bf16s_kernel<<<dim3(D_MODEL / 128, (B_ * L_) / 128), 256, 0, stream>>>(
        yb_hi, yb_lo, mow_hi, mow_lo, tmp2, B_ * L_, D_MODEL, D_INNER);

    // 10. output conv -> out [B,128,2048]
    conv_out_kernel<<<B_ * (L_ / 16), 128, 0, stream>>>(tmp2, out_conv_w, out);
}